// Round 1
// baseline (1451.423 us; speedup 1.0000x reference)
//
#include <hip/hip_runtime.h>
#include <math.h>

#define T_TOK 8192
#define C_DIM 768
#define H_DIM 64
// scale = sqrt(768) — the reference MULTIPLIES by c**0.5
#define SCALE_F 27.712812921102035f

// ---------------------------------------------------------------------------
// Kernel 1: QKV projection.  K/Q/V[t][h] = sum_c tokens[t][c] * W[c][h]
// 16 token rows per block, 192 threads (3 waves): thread t -> (which = t>>6,
// h = t&63).  Token rows staged in LDS (broadcast reads); W column reads are
// coalesced within each wave and L2-resident (3 x 196 KB).
// ---------------------------------------------------------------------------
#define PROJ_ROWS 16
__global__ __launch_bounds__(192) void qkv_proj_kernel(
    const float* __restrict__ tokens, const float* __restrict__ Wk,
    const float* __restrict__ Wq, const float* __restrict__ Wv,
    float* __restrict__ Kd, float* __restrict__ Qd, float* __restrict__ Vd)
{
    __shared__ float tok[PROJ_ROWS * C_DIM];           // 48 KB
    const int rb = blockIdx.x * PROJ_ROWS;
    const float4* src = (const float4*)(tokens + (size_t)rb * C_DIM);
    float4* dst = (float4*)tok;
    for (int i = threadIdx.x; i < PROJ_ROWS * C_DIM / 4; i += 192) dst[i] = src[i];
    __syncthreads();

    const int which = threadIdx.x >> 6;                // 0=K, 1=Q, 2=V
    const int h = threadIdx.x & 63;
    const float* __restrict__ W = (which == 0) ? Wk : (which == 1) ? Wq : Wv;
    float* __restrict__ outp = (which == 0) ? Kd : (which == 1) ? Qd : Vd;

    float acc[PROJ_ROWS];
#pragma unroll
    for (int r = 0; r < PROJ_ROWS; ++r) acc[r] = 0.f;
    for (int c = 0; c < C_DIM; ++c) {
        const float wv = W[c * H_DIM + h];
#pragma unroll
        for (int r = 0; r < PROJ_ROWS; ++r)
            acc[r] = fmaf(tok[r * C_DIM + c], wv, acc[r]);
    }
#pragma unroll
    for (int r = 0; r < PROJ_ROWS; ++r)
        outp[(size_t)(rb + r) * H_DIM + h] = acc[r];
}

// ---------------------------------------------------------------------------
// Kernel 2: causal flash attention, fp32.
// Grid: 128 blocks (one per 64-row Q tile), 256 threads = 4 waves.
// Lane l of every wave owns Q row (qbase + l); the 4 waves split the causal
// KV range (16-row tiles, strided by 4).  Each wave stages its K/V tile in
// wave-private LDS (no __syncthreads needed in the loop: single-wave in-order
// execution + compiler lgkmcnt waits order the LDS RAW).
// Per-wave online-softmax partials (m, l, o[64]) are written to global ws and
// merged by kernel 3.
// ---------------------------------------------------------------------------
#define BM 64      // q rows per block
#define BN 16      // kv rows per tile
#define NW 4       // waves per block

__global__ __launch_bounds__(256) void attn_fp32_kernel(
    const float* __restrict__ Qd, const float* __restrict__ Kd,
    const float* __restrict__ Vd,
    float* __restrict__ pm, float* __restrict__ pl, float* __restrict__ po)
{
    __shared__ float Ks[NW][BN][H_DIM];                // 16 KB
    __shared__ float Vs[NW][BN][H_DIM];                // 16 KB

    const int w    = threadIdx.x >> 6;
    const int lane = threadIdx.x & 63;
    const int qbase = blockIdx.x * BM;
    const int qrow  = qbase + lane;

    // q row -> registers (16 x float4)
    float q[H_DIM];
    {
        const float4* qsrc = (const float4*)(Qd + (size_t)qrow * H_DIM);
#pragma unroll
        for (int i = 0; i < H_DIM / 4; ++i) {
            float4 v = qsrc[i];
            q[4 * i + 0] = v.x; q[4 * i + 1] = v.y;
            q[4 * i + 2] = v.z; q[4 * i + 3] = v.w;
        }
    }

    float o[H_DIM];
#pragma unroll
    for (int d = 0; d < H_DIM; ++d) o[d] = 0.f;
    float m = -INFINITY, l = 0.f;

    const int maxrow = qbase + BM - 1;
    const int ntiles = maxrow / BN + 1;                // = 4*blockIdx.x + 4

    for (int tIdx = w; tIdx < ntiles; tIdx += NW) {
        const int kb = tIdx * BN;

        // wave-private cooperative tile load (coalesced float4)
        {
            const float4* ksrc = (const float4*)(Kd + (size_t)kb * H_DIM);
            const float4* vsrc = (const float4*)(Vd + (size_t)kb * H_DIM);
            float4* kdst = (float4*)&Ks[w][0][0];
            float4* vdst = (float4*)&Vs[w][0][0];
#pragma unroll
            for (int i = 0; i < BN * H_DIM / 4 / 64; ++i) {   // 4 iters
                kdst[lane + 64 * i] = ksrc[lane + 64 * i];
                vdst[lane + 64 * i] = vsrc[lane + 64 * i];
            }
        }
        // in-wave LDS write->read ordering is handled by lgkmcnt; keep the
        // compiler from migrating the reads above the writes:
        __builtin_amdgcn_wave_barrier();

        if (kb <= qrow) {                              // else: fully masked tile
            float s[BN];
#pragma unroll
            for (int j = 0; j < BN; ++j) {
                float acc = 0.f;
#pragma unroll
                for (int d = 0; d < H_DIM; ++d)
                    acc = fmaf(q[d], Ks[w][j][d], acc);
                s[j] = (kb + j <= qrow) ? acc * SCALE_F : -INFINITY;
            }
            float mt = m;
#pragma unroll
            for (int j = 0; j < BN; ++j) mt = fmaxf(mt, s[j]);
            const float alpha = expf(m - mt);          // m=-inf first time -> 0
            float lsum = 0.f;
#pragma unroll
            for (int j = 0; j < BN; ++j) { s[j] = expf(s[j] - mt); lsum += s[j]; }
            l = l * alpha + lsum;
            m = mt;
#pragma unroll
            for (int d = 0; d < H_DIM; ++d) o[d] *= alpha;
#pragma unroll
            for (int j = 0; j < BN; ++j) {
                const float p = s[j];
#pragma unroll
                for (int d = 0; d < H_DIM; ++d)
                    o[d] = fmaf(p, Vs[w][j][d], o[d]);
            }
        }
        __builtin_amdgcn_wave_barrier();
    }

    // write per-wave partials: index (qtile*NW + w, lane)
    const int pidx = blockIdx.x * NW + w;
    pm[pidx * BM + lane] = m;
    pl[pidx * BM + lane] = l;
    float4* podst = (float4*)(po + ((size_t)pidx * BM + lane) * H_DIM);
#pragma unroll
    for (int i = 0; i < H_DIM / 4; ++i) {
        float4 v; v.x = o[4*i]; v.y = o[4*i+1]; v.z = o[4*i+2]; v.w = o[4*i+3];
        podst[i] = v;
    }
}

// ---------------------------------------------------------------------------
// Kernel 3: merge the NW wave-partials per row:  out = sum_w o_w*e^{m_w-m} / l
// ---------------------------------------------------------------------------
__global__ __launch_bounds__(256) void combine_kernel(
    const float* __restrict__ pm, const float* __restrict__ pl,
    const float* __restrict__ po, float* __restrict__ out)
{
    const int idx = blockIdx.x * 256 + threadIdx.x;    // over T*H
    const int row = idx >> 6;
    const int d   = idx & 63;
    const int qt  = row >> 6;                          // q tile
    const int r   = row & 63;                          // lane within tile

    float mm = -INFINITY;
#pragma unroll
    for (int w = 0; w < NW; ++w)
        mm = fmaxf(mm, pm[(qt * NW + w) * BM + r]);
    float L = 0.f, val = 0.f;
#pragma unroll
    for (int w = 0; w < NW; ++w) {
        const int p = (qt * NW + w) * BM + r;
        const float sc = expf(pm[p] - mm);             // -inf -> 0, l_w=0 -> 0
        L   += pl[p] * sc;
        val += po[(size_t)p * H_DIM + d] * sc;
    }
    out[idx] = val / L;
}

// ---------------------------------------------------------------------------
extern "C" void kernel_launch(void* const* d_in, const int* in_sizes, int n_in,
                              void* d_out, int out_size, void* d_ws, size_t ws_size,
                              hipStream_t stream)
{
    const float* tokens = (const float*)d_in[0];
    const float* Wk = (const float*)d_in[1];
    const float* Wq = (const float*)d_in[2];
    const float* Wv = (const float*)d_in[3];
    float* out = (float*)d_out;

    // workspace layout (bytes):
    //   K: [0, 2MB)  Q: [2MB, 4MB)  V: [4MB, 6MB)
    //   pm: 6MB (+128KB)  pl: +128KB  po: 6.25MB..14.25MB
    char* ws = (char*)d_ws;
    float* Kd = (float*)(ws + 0);
    float* Qd = (float*)(ws + (size_t)2 * 1024 * 1024);
    float* Vd = (float*)(ws + (size_t)4 * 1024 * 1024);
    float* pm = (float*)(ws + (size_t)6 * 1024 * 1024);
    float* pl = (float*)(ws + (size_t)6 * 1024 * 1024 + 128 * 1024);
    float* po = (float*)(ws + (size_t)6 * 1024 * 1024 + 256 * 1024);

    qkv_proj_kernel<<<T_TOK / PROJ_ROWS, 192, 0, stream>>>(
        tokens, Wk, Wq, Wv, Kd, Qd, Vd);

    attn_fp32_kernel<<<T_TOK / BM, 256, 0, stream>>>(Qd, Kd, Vd, pm, pl, po);

    combine_kernel<<<T_TOK * H_DIM / 256, 256, 0, stream>>>(pm, pl, po, out);
}

// Round 2
// 621.924 us; speedup vs baseline: 2.3338x; 2.3338x over previous
//
#include <hip/hip_runtime.h>
#include <math.h>

#define T_TOK 8192
#define C_DIM 768
#define H_DIM 64
// scale = sqrt(768) — the reference MULTIPLIES by c**0.5
#define SCALE_F 27.712812921102035f

// ---------------------------------------------------------------------------
// Kernel 1: QKV projection.  K/Q/V[t][h] = sum_c tokens[t][c] * W[c][h]
// 16 token rows per block, 192 threads (3 waves): thread t -> (which = t>>6,
// h = t&63).  Token rows staged in LDS; read back as float4 (ds_read_b128
// broadcast) to quarter the LDS instruction count vs scalar reads.
// ---------------------------------------------------------------------------
#define PROJ_ROWS 16
__global__ __launch_bounds__(192) void qkv_proj_kernel(
    const float* __restrict__ tokens, const float* __restrict__ Wk,
    const float* __restrict__ Wq, const float* __restrict__ Wv,
    float* __restrict__ Kd, float* __restrict__ Qd, float* __restrict__ Vd)
{
    __shared__ float tok[PROJ_ROWS * C_DIM];           // 48 KB
    const int rb = blockIdx.x * PROJ_ROWS;
    const float4* src = (const float4*)(tokens + (size_t)rb * C_DIM);
    float4* dst = (float4*)tok;
    for (int i = threadIdx.x; i < PROJ_ROWS * C_DIM / 4; i += 192) dst[i] = src[i];
    __syncthreads();

    const int which = threadIdx.x >> 6;                // 0=K, 1=Q, 2=V
    const int h = threadIdx.x & 63;
    const float* __restrict__ W = (which == 0) ? Wk : (which == 1) ? Wq : Wv;
    float* __restrict__ outp = (which == 0) ? Kd : (which == 1) ? Qd : Vd;

    float acc[PROJ_ROWS];
#pragma unroll
    for (int r = 0; r < PROJ_ROWS; ++r) acc[r] = 0.f;
    for (int c = 0; c < C_DIM; c += 4) {
        const float w0 = W[(c + 0) * H_DIM + h];
        const float w1 = W[(c + 1) * H_DIM + h];
        const float w2 = W[(c + 2) * H_DIM + h];
        const float w3 = W[(c + 3) * H_DIM + h];
#pragma unroll
        for (int r = 0; r < PROJ_ROWS; ++r) {
            const float4 t = *(const float4*)&tok[r * C_DIM + c];
            acc[r] = fmaf(t.x, w0, fmaf(t.y, w1, fmaf(t.z, w2, fmaf(t.w, w3, acc[r]))));
        }
    }
#pragma unroll
    for (int r = 0; r < PROJ_ROWS; ++r)
        outp[(size_t)(rb + r) * H_DIM + h] = acc[r];
}

// ---------------------------------------------------------------------------
// Kernel 2: causal flash attention, fp32, KV-split for parallelism.
// Grid: 512 blocks = 128 q-tiles x 4 KV-splits, 512 threads = 8 waves.
// Block id -> (qt, sp) with complementary pairing: blocks b and b+256 (which
// land on the same CU under round-robin dispatch) get q-tiles summing to 127,
// so per-CU work is ~constant despite the causal triangle.
// Lane l owns Q row (qt*64 + l); wave w of split sp handles 16-row KV tiles
// t = sp*tps + w, +8, ... with tps = qt+1 (4*tps tiles total per q-tile).
// Wave-private LDS staging (no __syncthreads in the loop).
// Epilogue: two-phase cross-wave merge in LDS (exactly 64 KB), one partial
// (m, l, o[64]) per block per row -> global ws; kernel 3 merges the 4 splits.
// ---------------------------------------------------------------------------
#define BM 64      // q rows per block
#define BN 16      // kv rows per tile
#define NWAVE 8
#define NSPLIT 4

__global__ __launch_bounds__(512, 4) void attn_fp32_kernel(
    const float* __restrict__ Qd, const float* __restrict__ Kd,
    const float* __restrict__ Vd,
    float* __restrict__ pm, float* __restrict__ pl, float* __restrict__ po)
{
    // 16384 floats = 64 KB.  Phase 0 (tile loop): Ks[8][16][64] at [0,8192),
    // Vs[8][16][64] at [8192,16384), wave-private slices.
    // Phase A (m/L merge): m at [0,512), l at [512,1024).
    // Phase B (o sum-tree): 4 slots of [d][lane] 64x64 at slot*4096.
    __shared__ float lds[16384];

    const int w    = threadIdx.x >> 6;
    const int lane = threadIdx.x & 63;

    // block -> (qt, sp), pairing b and b+256 to complementary q-tiles
    const int b = blockIdx.x;
    const int j = b & 255;
    const int hb = b >> 8;                              // 0 or 1
    const int qt = (hb == 0) ? (j >> 1) : (127 - (j >> 1));
    const int sp = (hb << 1) | (j & 1);

    const int qbase = qt * BM;
    const int qrow  = qbase + lane;
    const int tps   = qt + 1;                           // tiles per split

    // q row -> registers
    float q[H_DIM];
    {
        const float4* qsrc = (const float4*)(Qd + (size_t)qrow * H_DIM);
#pragma unroll
        for (int i = 0; i < H_DIM / 4; ++i) {
            float4 v = qsrc[i];
            q[4 * i + 0] = v.x; q[4 * i + 1] = v.y;
            q[4 * i + 2] = v.z; q[4 * i + 3] = v.w;
        }
    }

    float o[H_DIM];
#pragma unroll
    for (int d = 0; d < H_DIM; ++d) o[d] = 0.f;
    float m = -INFINITY, l = 0.f;

    float* Ksw = lds + w * (BN * H_DIM);
    float* Vsw = lds + 8192 + w * (BN * H_DIM);

    const int tend = (sp + 1) * tps;
    for (int t = sp * tps + w; t < tend; t += NWAVE) {
        const int kb = t * BN;

        // wave-private cooperative tile load (coalesced float4)
        {
            const float4* ksrc = (const float4*)(Kd + (size_t)kb * H_DIM);
            const float4* vsrc = (const float4*)(Vd + (size_t)kb * H_DIM);
            float4* kdst = (float4*)Ksw;
            float4* vdst = (float4*)Vsw;
#pragma unroll
            for (int i = 0; i < BN * H_DIM / 4 / 64; ++i) {   // 4 iters
                kdst[lane + 64 * i] = ksrc[lane + 64 * i];
                vdst[lane + 64 * i] = vsrc[lane + 64 * i];
            }
        }
        __builtin_amdgcn_wave_barrier();   // order LDS RAW within the wave

        if (kb <= qrow) {                  // else: fully masked for this lane
            float s[BN];
#pragma unroll
            for (int jj = 0; jj < BN; ++jj) {
                float acc = 0.f;
#pragma unroll
                for (int d = 0; d < H_DIM; ++d)
                    acc = fmaf(q[d], Ksw[jj * H_DIM + d], acc);
                s[jj] = (kb + jj <= qrow) ? acc * SCALE_F : -INFINITY;
            }
            float mt = m;
#pragma unroll
            for (int jj = 0; jj < BN; ++jj) mt = fmaxf(mt, s[jj]);
            const float alpha = expf(m - mt);          // m=-inf first time -> 0
            float lsum = 0.f;
#pragma unroll
            for (int jj = 0; jj < BN; ++jj) { s[jj] = expf(s[jj] - mt); lsum += s[jj]; }
            l = l * alpha + lsum;
            m = mt;
#pragma unroll
            for (int d = 0; d < H_DIM; ++d) o[d] *= alpha;
#pragma unroll
            for (int jj = 0; jj < BN; ++jj) {
                const float p = s[jj];
#pragma unroll
                for (int d = 0; d < H_DIM; ++d)
                    o[d] = fmaf(p, Vsw[jj * H_DIM + d], o[d]);
            }
        }
        __builtin_amdgcn_wave_barrier();
    }

    // ---- Phase A: block max + block L, per q-row ----
    __syncthreads();                       // staging buffers now dead
    lds[w * 64 + lane] = m;
    lds[512 + w * 64 + lane] = l;
    __syncthreads();
    float mfin = -INFINITY;
#pragma unroll
    for (int k = 0; k < NWAVE; ++k) mfin = fmaxf(mfin, lds[k * 64 + lane]);
    float L = 0.f;
#pragma unroll
    for (int k = 0; k < NWAVE; ++k) {
        const float mk = lds[k * 64 + lane];
        const float lk = lds[512 + k * 64 + lane];
        L += (mk > -INFINITY) ? lk * expf(mk - mfin) : 0.f;
    }
    {
        const float a = (m > -INFINITY) ? expf(m - mfin) : 0.f;
#pragma unroll
        for (int d = 0; d < H_DIM; ++d) o[d] *= a;
    }
    __syncthreads();                       // before reusing lds[0,1024)

    // ---- Phase B: o sum-tree across waves (transposed [d][lane]: no bank
    // conflicts; slot stride 4096 floats) ----
    for (int s = NWAVE / 2; s >= 1; s >>= 1) {
        if (w >= s && w < 2 * s) {
            float* ob = lds + (w - s) * 4096;
#pragma unroll
            for (int d = 0; d < H_DIM; ++d) ob[d * 64 + lane] = o[d];
        }
        __syncthreads();
        if (w < s) {
            const float* ob = lds + w * 4096;
#pragma unroll
            for (int d = 0; d < H_DIM; ++d) o[d] += ob[d * 64 + lane];
        }
        __syncthreads();
    }

    if (w == 0) {
        const int pidx = qt * NSPLIT + sp;
        pm[pidx * BM + lane] = mfin;
        pl[pidx * BM + lane] = L;
        float4* podst = (float4*)(po + ((size_t)pidx * BM + lane) * H_DIM);
#pragma unroll
        for (int i = 0; i < H_DIM / 4; ++i) {
            float4 v; v.x = o[4*i]; v.y = o[4*i+1]; v.z = o[4*i+2]; v.w = o[4*i+3];
            podst[i] = v;
        }
    }
}

// ---------------------------------------------------------------------------
// Kernel 3: merge the NSPLIT split-partials per row.
// ---------------------------------------------------------------------------
__global__ __launch_bounds__(256) void combine_kernel(
    const float* __restrict__ pm, const float* __restrict__ pl,
    const float* __restrict__ po, float* __restrict__ out)
{
    const int idx = blockIdx.x * 256 + threadIdx.x;    // over T*H
    const int row = idx >> 6;
    const int d   = idx & 63;
    const int qt  = row >> 6;                          // q tile
    const int r   = row & 63;                          // lane within tile

    float mm = -INFINITY;
#pragma unroll
    for (int s = 0; s < NSPLIT; ++s)
        mm = fmaxf(mm, pm[(qt * NSPLIT + s) * BM + r]);
    float L = 0.f, val = 0.f;
#pragma unroll
    for (int s = 0; s < NSPLIT; ++s) {
        const int p = (qt * NSPLIT + s) * BM + r;
        const float mp = pm[p];
        const float sc = (mp > -INFINITY) ? expf(mp - mm) : 0.f;
        L   += pl[p] * sc;
        val += po[(size_t)p * H_DIM + d] * sc;
    }
    out[idx] = val / L;
}

// ---------------------------------------------------------------------------
extern "C" void kernel_launch(void* const* d_in, const int* in_sizes, int n_in,
                              void* d_out, int out_size, void* d_ws, size_t ws_size,
                              hipStream_t stream)
{
    const float* tokens = (const float*)d_in[0];
    const float* Wk = (const float*)d_in[1];
    const float* Wq = (const float*)d_in[2];
    const float* Wv = (const float*)d_in[3];
    float* out = (float*)d_out;

    // workspace layout (bytes), total 14.25 MB (same as round 1):
    //   K: [0, 2MB)  Q: [2MB, 4MB)  V: [4MB, 6MB)
    //   pm: 6MB..+128KB  pl: +128KB..+256KB  po: +256KB..+8.25MB
    char* ws = (char*)d_ws;
    float* Kd = (float*)(ws + 0);
    float* Qd = (float*)(ws + (size_t)2 * 1024 * 1024);
    float* Vd = (float*)(ws + (size_t)4 * 1024 * 1024);
    float* pm = (float*)(ws + (size_t)6 * 1024 * 1024);
    float* pl = (float*)(ws + (size_t)6 * 1024 * 1024 + 128 * 1024);
    float* po = (float*)(ws + (size_t)6 * 1024 * 1024 + 256 * 1024);

    qkv_proj_kernel<<<T_TOK / PROJ_ROWS, 192, 0, stream>>>(
        tokens, Wk, Wq, Wv, Kd, Qd, Vd);

    attn_fp32_kernel<<<128 * NSPLIT, 512, 0, stream>>>(Qd, Kd, Vd, pm, pl, po);

    combine_kernel<<<T_TOK * H_DIM / 256, 256, 0, stream>>>(pm, pl, po, out);
}

// Round 3
// 256.059 us; speedup vs baseline: 5.6683x; 2.4288x over previous
//
#include <hip/hip_runtime.h>
#include <math.h>

#define T_TOK 8192
#define C_DIM 768
#define H_DIM 64
// scale = sqrt(768) — the reference MULTIPLIES by c**0.5
#define SCALE_F 27.712812921102035f
#define NSPLIT 4

typedef _Float16 half8 __attribute__((ext_vector_type(8)));
typedef float floatx4 __attribute__((ext_vector_type(4)));

#define MFMA16(a, b, c) __builtin_amdgcn_mfma_f32_16x16x32_f16(a, b, c, 0, 0, 0)
// wait lgkmcnt(0) only: vmcnt=0x3F (bits[3:0]=0xF, [15:14]=3), expcnt=7, lgkm=0
#define WAIT_LGKM0() __builtin_amdgcn_s_waitcnt(0xC07F)

// ---------------------------------------------------------------------------
// Kernel 1: QKV projection (fp32 math) -> f16 hi/lo for Q,K; f16 V^T.
// 8 token rows per block, 192 threads: thread -> (which = t>>6, h = t&63).
// hi/lo split: x = hi + lo with |x - hi - lo| <= 2^-22 |x|  (f16 RNE twice),
// so MFMA QK^T via hi*hi + hi*lo + lo*hi keeps logit error ~1e-4 even after
// the x27.7 scale (single f16/bf16 would flip argmax rows -> absmax ~1).
// ---------------------------------------------------------------------------
#define PROJ_ROWS 8
__global__ __launch_bounds__(192) void qkv_proj_kernel(
    const float* __restrict__ tokens, const float* __restrict__ Wk,
    const float* __restrict__ Wq, const float* __restrict__ Wv,
    _Float16* __restrict__ Khi, _Float16* __restrict__ Klo,
    _Float16* __restrict__ Qhi, _Float16* __restrict__ Qlo,
    _Float16* __restrict__ VT)
{
    __shared__ float tok[PROJ_ROWS * C_DIM];           // 24 KB
    const int rb = blockIdx.x * PROJ_ROWS;
    const float4* src = (const float4*)(tokens + (size_t)rb * C_DIM);
    float4* dst = (float4*)tok;
    for (int i = threadIdx.x; i < PROJ_ROWS * C_DIM / 4; i += 192) dst[i] = src[i];
    __syncthreads();

    const int which = threadIdx.x >> 6;                // 0=K, 1=Q, 2=V
    const int h = threadIdx.x & 63;
    const float* __restrict__ W = (which == 0) ? Wk : (which == 1) ? Wq : Wv;

    float acc[PROJ_ROWS];
#pragma unroll
    for (int r = 0; r < PROJ_ROWS; ++r) acc[r] = 0.f;
    for (int c = 0; c < C_DIM; c += 4) {
        const float w0 = W[(c + 0) * H_DIM + h];
        const float w1 = W[(c + 1) * H_DIM + h];
        const float w2 = W[(c + 2) * H_DIM + h];
        const float w3 = W[(c + 3) * H_DIM + h];
#pragma unroll
        for (int r = 0; r < PROJ_ROWS; ++r) {
            const float4 t = *(const float4*)&tok[r * C_DIM + c];
            acc[r] = fmaf(t.x, w0, fmaf(t.y, w1, fmaf(t.z, w2, fmaf(t.w, w3, acc[r]))));
        }
    }

    if (which == 2) {
        half8 v;
#pragma unroll
        for (int r = 0; r < PROJ_ROWS; ++r) v[r] = (_Float16)acc[r];
        *(half8*)(VT + (size_t)h * T_TOK + rb) = v;    // V^T[h][rb..rb+8), 16B
    } else {
        _Float16* __restrict__ hiP = (which == 0) ? Khi : Qhi;
        _Float16* __restrict__ loP = (which == 0) ? Klo : Qlo;
#pragma unroll
        for (int r = 0; r < PROJ_ROWS; ++r) {
            const float a = acc[r];
            const _Float16 hi = (_Float16)a;
            const _Float16 lo = (_Float16)(a - (float)hi);
            hiP[(size_t)(rb + r) * H_DIM + h] = hi;    // coalesced across h
            loP[(size_t)(rb + r) * H_DIM + h] = lo;
        }
    }
}

// ---------------------------------------------------------------------------
// Kernel 2: causal flash attention via mfma_f32_16x16x32_f16.
// Grid: 512 blocks = 128 q-tiles x 4 KV-splits (complementary-paired for
// balance), 256 threads = 4 waves.  Wave w owns Q rows [qt*64+w*16, +16);
// iterates 64-wide KV tiles t = sp, sp+4, ..., qt (waves independent — NO
// __syncthreads anywhere in the loop).
// Per tile: S strip 16x64 = 4 nb x (3 MFMA hi/lo x 2 kstep); online softmax
// in C-layout (row = quad*4+reg, col = nb*16+l15) with quad-group shfl_xor
// row-max; P -> f16 -> wave-private padded LDS -> A-layout read; PV = 8 MFMA
// with V^T B-frags straight from global (L2-resident).
// l-sum is kept lane-local and reduced once in the epilogue.
// ---------------------------------------------------------------------------
__global__ __launch_bounds__(256) void attn_mfma_kernel(
    const _Float16* __restrict__ Qhi, const _Float16* __restrict__ Qlo,
    const _Float16* __restrict__ Khi, const _Float16* __restrict__ Klo,
    const _Float16* __restrict__ VT,
    float* __restrict__ pm, float* __restrict__ pl, float* __restrict__ po)
{
    // P scratch: 16 rows x 72 f16 per wave (stride 72: rows stay 16B-aligned,
    // breaks the power-of-2 bank stride).  4 waves x 2304 B = 9.2 KB.
    __shared__ __align__(16) _Float16 Ps[4][16 * 72];

    const int w    = threadIdx.x >> 6;
    const int lane = threadIdx.x & 63;
    const int l15  = lane & 15;
    const int quad = lane >> 4;

    // block -> (qt, sp); pair b and b+256 to complementary q-tiles
    const int b  = blockIdx.x;
    const int j  = b & 255;
    const int hb = b >> 8;
    const int qt = (hb == 0) ? (j >> 1) : (127 - (j >> 1));
    const int sp = (hb << 1) | (j & 1);

    const int qbase   = qt * 64;
    const int wrow0   = qbase + w * 16;        // wave's first q row
    const int rowbase = wrow0 + quad * 4;      // + reg = this lane's rows

    // Q A-frags (lane: m = l15 -> q row, k = quad*8+j (+32*kstep))
    half8 qh[2], ql[2];
    {
        const size_t qo = (size_t)(wrow0 + l15) * H_DIM + quad * 8;
        qh[0] = *(const half8*)(Qhi + qo);
        qh[1] = *(const half8*)(Qhi + qo + 32);
        ql[0] = *(const half8*)(Qlo + qo);
        ql[1] = *(const half8*)(Qlo + qo + 32);
    }

    floatx4 O[4];
#pragma unroll
    for (int nb = 0; nb < 4; ++nb) O[nb] = 0;
    float mreg[4] = {-INFINITY, -INFINITY, -INFINITY, -INFINITY};
    float lreg[4] = {0.f, 0.f, 0.f, 0.f};      // lane-local partial sums

    const size_t koff = (size_t)l15 * H_DIM + quad * 8;   // within K tile
    const _Float16* vtb[4];
#pragma unroll
    for (int nb = 0; nb < 4; ++nb)
        vtb[nb] = VT + (size_t)(nb * 16 + l15) * T_TOK + quad * 8;

    for (int t = sp; t <= qt; t += NSPLIT) {
        const int kb = t * 64;

        // K B-frags (lane: n = l15 -> k row, k = quad*8+j): 16B contiguous
        const _Float16* kh = Khi + (size_t)kb * H_DIM + koff;
        const _Float16* kl = Klo + (size_t)kb * H_DIM + koff;
        half8 bh[4][2], bl[4][2];
#pragma unroll
        for (int nb = 0; nb < 4; ++nb) {
#pragma unroll
            for (int ks = 0; ks < 2; ++ks) {
                bh[nb][ks] = *(const half8*)(kh + nb * 16 * H_DIM + ks * 32);
                bl[nb][ks] = *(const half8*)(kl + nb * 16 * H_DIM + ks * 32);
            }
        }

        // S = (qhi+qlo)(khi+klo)^T ~ hi*hi + hi*lo + lo*hi
        floatx4 S[4];
#pragma unroll
        for (int nb = 0; nb < 4; ++nb) {
            floatx4 s = 0;
#pragma unroll
            for (int ks = 0; ks < 2; ++ks) {
                s = MFMA16(qh[ks], bh[nb][ks], s);
                s = MFMA16(qh[ks], bl[nb][ks], s);
                s = MFMA16(ql[ks], bh[nb][ks], s);
            }
            S[nb] = s;
        }

        // scale + causal mask (wave-uniform fast path skips the mask)
        float sv[4][4];
#pragma unroll
        for (int nb = 0; nb < 4; ++nb)
#pragma unroll
            for (int r = 0; r < 4; ++r) sv[nb][r] = S[nb][r] * SCALE_F;
        if (kb + 63 > wrow0) {
#pragma unroll
            for (int nb = 0; nb < 4; ++nb) {
                const int col = kb + nb * 16 + l15;
#pragma unroll
                for (int r = 0; r < 4; ++r)
                    if (col > rowbase + r) sv[nb][r] = -INFINITY;
            }
        }

        // online softmax, one reduction chain per reg-row
#pragma unroll
        for (int r = 0; r < 4; ++r) {
            float rm = fmaxf(fmaxf(sv[0][r], sv[1][r]), fmaxf(sv[2][r], sv[3][r]));
            rm = fmaxf(rm, __shfl_xor(rm, 1));
            rm = fmaxf(rm, __shfl_xor(rm, 2));
            rm = fmaxf(rm, __shfl_xor(rm, 4));
            rm = fmaxf(rm, __shfl_xor(rm, 8));
            const float mnew = fmaxf(mreg[r], rm);
            const float alpha = (mreg[r] == mnew) ? 1.0f : __expf(mreg[r] - mnew);
            float psum = 0.f;
#pragma unroll
            for (int nb = 0; nb < 4; ++nb) {
                const float svv = sv[nb][r];
                const float p = (svv == -INFINITY) ? 0.f : __expf(svv - mnew);
                psum += p;
                Ps[w][(quad * 4 + r) * 72 + nb * 16 + l15] = (_Float16)p;
            }
            lreg[r] = lreg[r] * alpha + psum;
            mreg[r] = mnew;
#pragma unroll
            for (int nb = 0; nb < 4; ++nb) O[nb][r] *= alpha;
        }

        // P: C-layout -> A-layout via LDS (wave-private; order + drain)
        __builtin_amdgcn_wave_barrier();
        WAIT_LGKM0();
        __builtin_amdgcn_wave_barrier();
        const half8 pa0 = *(const half8*)&Ps[w][l15 * 72 + quad * 8];
        const half8 pa1 = *(const half8*)&Ps[w][l15 * 72 + 32 + quad * 8];

        // PV: B-frags from V^T (lane: n = l15 -> d, k contiguous along t)
#pragma unroll
        for (int nb = 0; nb < 4; ++nb) {
            const half8 v0 = *(const half8*)(vtb[nb] + kb);
            const half8 v1 = *(const half8*)(vtb[nb] + kb + 32);
            O[nb] = MFMA16(pa0, v0, O[nb]);
            O[nb] = MFMA16(pa1, v1, O[nb]);
        }
        __builtin_amdgcn_wave_barrier();
    }

    // epilogue: reduce lane-local l across the 16-lane quad group, write
    // per-(qt,sp) partials.  (alpha factors are row-uniform, so the lane sum
    // is exact.)
#pragma unroll
    for (int r = 0; r < 4; ++r) {
        float s = lreg[r];
        s += __shfl_xor(s, 1);
        s += __shfl_xor(s, 2);
        s += __shfl_xor(s, 4);
        s += __shfl_xor(s, 8);
        lreg[r] = s;
    }

    const int pidx = qt * NSPLIT + sp;
    float* pob = po + ((size_t)pidx * 64 + w * 16 + quad * 4) * 64 + l15;
#pragma unroll
    for (int r = 0; r < 4; ++r)
#pragma unroll
        for (int nb = 0; nb < 4; ++nb)
            pob[r * 64 + nb * 16] = O[nb][r];
    if (l15 == 0) {
#pragma unroll
        for (int r = 0; r < 4; ++r) {
            pm[pidx * 64 + w * 16 + quad * 4 + r] = mreg[r];
            pl[pidx * 64 + w * 16 + quad * 4 + r] = lreg[r];
        }
    }
}

// ---------------------------------------------------------------------------
// Kernel 3: merge the NSPLIT split-partials per row.
// ---------------------------------------------------------------------------
__global__ __launch_bounds__(256) void combine_kernel(
    const float* __restrict__ pm, const float* __restrict__ pl,
    const float* __restrict__ po, float* __restrict__ out)
{
    const int idx = blockIdx.x * 256 + threadIdx.x;    // over T*H
    const int row = idx >> 6;
    const int d   = idx & 63;
    const int qt  = row >> 6;
    const int r   = row & 63;

    float mm = -INFINITY;
#pragma unroll
    for (int s = 0; s < NSPLIT; ++s)
        mm = fmaxf(mm, pm[(qt * NSPLIT + s) * 64 + r]);
    float L = 0.f, val = 0.f;
#pragma unroll
    for (int s = 0; s < NSPLIT; ++s) {
        const int p = (qt * NSPLIT + s) * 64 + r;
        const float mp = pm[p];
        const float sc = (mp > -INFINITY) ? __expf(mp - mm) : 0.f;
        L   += pl[p] * sc;
        val += po[(size_t)p * H_DIM + d] * sc;
    }
    out[idx] = val / L;
}

// ---------------------------------------------------------------------------
extern "C" void kernel_launch(void* const* d_in, const int* in_sizes, int n_in,
                              void* d_out, int out_size, void* d_ws, size_t ws_size,
                              hipStream_t stream)
{
    const float* tokens = (const float*)d_in[0];
    const float* Wk = (const float*)d_in[1];
    const float* Wq = (const float*)d_in[2];
    const float* Wv = (const float*)d_in[3];
    float* out = (float*)d_out;

    // ws layout (bytes), total 13.25 MB:
    //   Khi 0..1MB, Klo 1..2MB, Qhi 2..3MB, Qlo 3..4MB, VT 4..5MB
    //   pm 5MB..+128KB, pl +128KB..+256KB, po 5.25MB..13.25MB
    char* ws = (char*)d_ws;
    const size_t MB = 1024 * 1024;
    _Float16* Khi = (_Float16*)(ws + 0 * MB);
    _Float16* Klo = (_Float16*)(ws + 1 * MB);
    _Float16* Qhi = (_Float16*)(ws + 2 * MB);
    _Float16* Qlo = (_Float16*)(ws + 3 * MB);
    _Float16* VT  = (_Float16*)(ws + 4 * MB);
    float* pm = (float*)(ws + 5 * MB);
    float* pl = (float*)(ws + 5 * MB + 128 * 1024);
    float* po = (float*)(ws + 5 * MB + 256 * 1024);

    qkv_proj_kernel<<<T_TOK / PROJ_ROWS, 192, 0, stream>>>(
        tokens, Wk, Wq, Wv, Khi, Klo, Qhi, Qlo, VT);

    attn_mfma_kernel<<<128 * NSPLIT, 256, 0, stream>>>(
        Qhi, Qlo, Khi, Klo, VT, pm, pl, po);

    combine_kernel<<<T_TOK * H_DIM / 256, 256, 0, stream>>>(pm, pl, po, out);
}

// Round 4
// 172.953 us; speedup vs baseline: 8.3920x; 1.4805x over previous
//
#include <hip/hip_runtime.h>
#include <math.h>

#define T_TOK 8192
#define C_DIM 768
#define H_DIM 64
// reference MULTIPLIES by c**0.5; we work in exp2 domain: scale * log2(e)
#define SCALE_LOG2E (27.712812921102035f * 1.4426950408889634f)
#define NSPLIT 4

typedef _Float16 half8 __attribute__((ext_vector_type(8)));
typedef float floatx4 __attribute__((ext_vector_type(4)));

#define MFMA16(a, b, c) __builtin_amdgcn_mfma_f32_16x16x32_f16(a, b, c, 0, 0, 0)
// wait lgkmcnt(0) only: vmcnt=0x3F, expcnt=7, lgkm=0
#define WAIT_LGKM0() __builtin_amdgcn_s_waitcnt(0xC07F)
#define EXP2F(x) __builtin_amdgcn_exp2f(x)

// Fragment layouts in workspace (all 1KB frags, perfectly coalesced b128/lane):
//   WF[mat][kt(24)][nb(4)][hl(2)][512 f16]   = W[kt*32+quad*8+j][nb*16+l15]
//   KF[t(128)][nb(4)][ks(2)][hl(2)][512 f16] = K[t*64+nb*16+l15][ks*32+quad*8+j]
//   QF[rb(512)][ks(2)][hl(2)][512 f16]       = Q[rb*16+l15][ks*32+quad*8+j]
//   VF[t(128)][nb(4)][ks(2)][512 f16]        = V[t*64+ks*32+quad*8+j][nb*16+l15]

// ---------------------------------------------------------------------------
// Kernel 0: W fp32 -> hi/lo f16 B-frags.  288 blocks x 64 threads.
// ---------------------------------------------------------------------------
__global__ __launch_bounds__(64) void wconvert_kernel(
    const float* __restrict__ Wk, const float* __restrict__ Wq,
    const float* __restrict__ Wv, _Float16* __restrict__ WF)
{
    const int b = blockIdx.x;                  // 3*24*4
    const int mat = b / 96, rem = b % 96, kt = rem >> 2, nb = rem & 3;
    const int lane = threadIdx.x & 63, l15 = lane & 15, quad = lane >> 4;
    const float* __restrict__ W = (mat == 0) ? Wk : (mat == 1) ? Wq : Wv;

    half8 h, l;
#pragma unroll
    for (int j = 0; j < 8; ++j) {
        const float v = W[(kt * 32 + quad * 8 + j) * H_DIM + nb * 16 + l15];
        const _Float16 hv = (_Float16)v;
        h[j] = hv;
        l[j] = (_Float16)(v - (float)hv);
    }
    _Float16* dst = WF + ((((size_t)mat * 24 + kt) * 4 + nb) * 2) * 512 + lane * 8;
    *(half8*)dst = h;
    *(half8*)(dst + 512) = l;
}

// ---------------------------------------------------------------------------
// Kernel 1: MFMA projection.  768 blocks x 64 threads: mat = b>>8, mi = b&255.
// One wave computes rows [mi*32, +32) x all 64 cols of its matrix.
// K/Q: 3-pass hi/lo (fp32-grade result), V: 1-pass (f16-grade is enough).
// Epilogue: LDS transpose -> frag-order stores (hi/lo split for K/Q).
// ---------------------------------------------------------------------------
__global__ __launch_bounds__(64) void proj_kernel(
    const float* __restrict__ tokens, const _Float16* __restrict__ WF,
    _Float16* __restrict__ KF, _Float16* __restrict__ QF,
    _Float16* __restrict__ VF)
{
    __shared__ float Cb[32 * 64];              // 8 KB
    const int b = blockIdx.x;
    const int mat = b >> 8, mi = b & 255;
    const int lane = threadIdx.x & 63, l15 = lane & 15, quad = lane >> 4;
    const int row0 = mi * 32;

    floatx4 acc[2][4];
#pragma unroll
    for (int mb = 0; mb < 2; ++mb)
#pragma unroll
        for (int nb = 0; nb < 4; ++nb) acc[mb][nb] = 0;

    const _Float16* __restrict__ wfm = WF + (size_t)mat * 24 * 4 * 2 * 512;

    for (int kt = 0; kt < 24; ++kt) {
        // A-frags: tokens fp32 -> hi/lo f16 on the fly
        half8 ah[2], al[2];
#pragma unroll
        for (int mb = 0; mb < 2; ++mb) {
            const float* xp = tokens + (size_t)(row0 + mb * 16 + l15) * C_DIM
                              + kt * 32 + quad * 8;
            const float4 x0 = *(const float4*)xp;
            const float4 x1 = *(const float4*)(xp + 4);
            const float xs[8] = {x0.x, x0.y, x0.z, x0.w, x1.x, x1.y, x1.z, x1.w};
            half8 h, l;
#pragma unroll
            for (int e = 0; e < 8; ++e) {
                const _Float16 hv = (_Float16)xs[e];
                h[e] = hv;
                l[e] = (_Float16)(xs[e] - (float)hv);
            }
            ah[mb] = h; al[mb] = l;
        }
#pragma unroll
        for (int nb = 0; nb < 4; ++nb) {
            const _Float16* wp = wfm + (((size_t)kt * 4 + nb) * 2) * 512 + lane * 8;
            const half8 wh = *(const half8*)wp;
            if (mat != 2) {
                const half8 wl = *(const half8*)(wp + 512);
#pragma unroll
                for (int mb = 0; mb < 2; ++mb) {
                    acc[mb][nb] = MFMA16(ah[mb], wh, acc[mb][nb]);
                    acc[mb][nb] = MFMA16(ah[mb], wl, acc[mb][nb]);
                    acc[mb][nb] = MFMA16(al[mb], wh, acc[mb][nb]);
                }
            } else {
#pragma unroll
                for (int mb = 0; mb < 2; ++mb)
                    acc[mb][nb] = MFMA16(ah[mb], wh, acc[mb][nb]);
            }
        }
    }

    // C-layout -> LDS
#pragma unroll
    for (int mb = 0; mb < 2; ++mb)
#pragma unroll
        for (int nb = 0; nb < 4; ++nb)
#pragma unroll
            for (int r = 0; r < 4; ++r)
                Cb[(mb * 16 + quad * 4 + r) * 64 + nb * 16 + l15] = acc[mb][nb][r];
    __builtin_amdgcn_wave_barrier();
    WAIT_LGKM0();
    __builtin_amdgcn_wave_barrier();

    if (mat != 2) {                            // K (mat 0) / Q (mat 1)
#pragma unroll
        for (int nbL = 0; nbL < 2; ++nbL) {
#pragma unroll
            for (int ks = 0; ks < 2; ++ks) {
                const float* cp = Cb + (nbL * 16 + l15) * 64 + ks * 32 + quad * 8;
                const float4 c0 = *(const float4*)cp;
                const float4 c1 = *(const float4*)(cp + 4);
                const float cs[8] = {c0.x, c0.y, c0.z, c0.w, c1.x, c1.y, c1.z, c1.w};
                half8 h, l;
#pragma unroll
                for (int e = 0; e < 8; ++e) {
                    const _Float16 hv = (_Float16)cs[e];
                    h[e] = hv;
                    l[e] = (_Float16)(cs[e] - (float)hv);
                }
                _Float16* dst;
                if (mat == 0) {
                    const int t = mi >> 1, nb = (mi & 1) * 2 + nbL;
                    dst = KF + (((size_t)(t * 4 + nb) * 2 + ks) * 2) * 512 + lane * 8;
                } else {
                    const int rb = mi * 2 + nbL;
                    dst = QF + (((size_t)rb * 2 + ks) * 2) * 512 + lane * 8;
                }
                *(half8*)dst = h;
                *(half8*)(dst + 512) = l;
            }
        }
    } else {                                   // V
        const int t = mi >> 1, ks = mi & 1;
#pragma unroll
        for (int nb = 0; nb < 4; ++nb) {
            half8 h;
#pragma unroll
            for (int j = 0; j < 8; ++j)
                h[j] = (_Float16)Cb[(quad * 8 + j) * 64 + nb * 16 + l15];
            *(half8*)(VF + ((size_t)(t * 4 + nb) * 2 + ks) * 512 + lane * 8) = h;
        }
    }
}

// ---------------------------------------------------------------------------
// Kernel 2: causal flash attention, all-coalesced frag loads.
// 512 blocks = 128 qt x 4 sp, 256 threads = 4 waves:
//   mhalf = w&1 (rows mhalf*32..+32), ss = w>>1 (KV subsplit).
// Wave iterates t = sp + 4*ss, step 8, up to qt; B-frags (KF/VF) reused
// across its 2 m-blocks.  No __syncthreads in the loop.  Epilogue merges the
// 2 subsplits in LDS -> 4 partials/row for kernel 3.  exp2-domain softmax.
// ---------------------------------------------------------------------------
__global__ __launch_bounds__(256, 2) void attn_mfma_kernel(
    const _Float16* __restrict__ QF, const _Float16* __restrict__ KF,
    const _Float16* __restrict__ VF,
    float* __restrict__ pm, float* __restrict__ pl, float* __restrict__ po)
{
    // Ps: [w][mb][16 rows][stride 72 f16] = 18432 B; merge phase reuses it.
    __shared__ __align__(16) float smemf[4608];
    _Float16* Ps = (_Float16*)smemf;

    const int w = threadIdx.x >> 6, lane = threadIdx.x & 63;
    const int l15 = lane & 15, quad = lane >> 4;
    const int mhalf = w & 1, ss = w >> 1;

    const int b = blockIdx.x;
    const int j = b & 255, hb = b >> 8;
    const int qt = (hb == 0) ? (j >> 1) : (127 - (j >> 1));
    const int sp = (hb << 1) | (j & 1);

    const int qbase = qt * 64;
    const int wrow0 = qbase + mhalf * 32;

    // Q A-frags (hi/lo), loaded once
    half8 qh[2][2], ql[2][2];
#pragma unroll
    for (int mb = 0; mb < 2; ++mb)
#pragma unroll
        for (int ks = 0; ks < 2; ++ks) {
            const int rb = qt * 4 + mhalf * 2 + mb;
            const _Float16* qp = QF + (((size_t)rb * 2 + ks) * 2) * 512 + lane * 8;
            qh[mb][ks] = *(const half8*)qp;
            ql[mb][ks] = *(const half8*)(qp + 512);
        }

    floatx4 O[2][4];
#pragma unroll
    for (int mb = 0; mb < 2; ++mb)
#pragma unroll
        for (int nb = 0; nb < 4; ++nb) O[mb][nb] = 0;
    float mreg[2][4], lreg[2][4];
#pragma unroll
    for (int mb = 0; mb < 2; ++mb)
#pragma unroll
        for (int r = 0; r < 4; ++r) { mreg[mb][r] = -INFINITY; lreg[mb][r] = 0.f; }

    for (int t = sp + 4 * ss; t <= qt; t += 8) {
        const int kb = t * 64;

        // K B-frags: 16 coalesced 1KB loads
        half8 bh[4][2], bl[4][2];
#pragma unroll
        for (int nb = 0; nb < 4; ++nb)
#pragma unroll
            for (int ks = 0; ks < 2; ++ks) {
                const _Float16* kp =
                    KF + (((size_t)(t * 4 + nb) * 2 + ks) * 2) * 512 + lane * 8;
                bh[nb][ks] = *(const half8*)kp;
                bl[nb][ks] = *(const half8*)(kp + 512);
            }

        // S = Q K^T (hi*hi + hi*lo + lo*hi), scaled into exp2 domain
        float sv[2][4][4];
#pragma unroll
        for (int mb = 0; mb < 2; ++mb)
#pragma unroll
            for (int nb = 0; nb < 4; ++nb) {
                floatx4 s = 0;
#pragma unroll
                for (int ks = 0; ks < 2; ++ks) {
                    s = MFMA16(qh[mb][ks], bh[nb][ks], s);
                    s = MFMA16(qh[mb][ks], bl[nb][ks], s);
                    s = MFMA16(ql[mb][ks], bh[nb][ks], s);
                }
#pragma unroll
                for (int r = 0; r < 4; ++r) sv[mb][nb][r] = s[r] * SCALE_LOG2E;
            }

        if (kb + 63 > wrow0) {                 // diagonal tile: causal mask
#pragma unroll
            for (int mb = 0; mb < 2; ++mb) {
                const int rowbase = wrow0 + mb * 16 + quad * 4;
#pragma unroll
                for (int nb = 0; nb < 4; ++nb) {
                    const int col = kb + nb * 16 + l15;
#pragma unroll
                    for (int r = 0; r < 4; ++r)
                        if (col > rowbase + r) sv[mb][nb][r] = -INFINITY;
                }
            }
        }

        // online softmax (exp2 domain)
#pragma unroll
        for (int mb = 0; mb < 2; ++mb) {
#pragma unroll
            for (int r = 0; r < 4; ++r) {
                float rm = fmaxf(fmaxf(sv[mb][0][r], sv[mb][1][r]),
                                 fmaxf(sv[mb][2][r], sv[mb][3][r]));
                rm = fmaxf(rm, __shfl_xor(rm, 1));
                rm = fmaxf(rm, __shfl_xor(rm, 2));
                rm = fmaxf(rm, __shfl_xor(rm, 4));
                rm = fmaxf(rm, __shfl_xor(rm, 8));
                const float mnew = fmaxf(mreg[mb][r], rm);
                const float alpha = EXP2F(mreg[mb][r] - mnew);   // -inf -> 0
                float psum = 0.f;
#pragma unroll
                for (int nb = 0; nb < 4; ++nb) {
                    const float p = EXP2F(sv[mb][nb][r] - mnew);  // -inf -> 0
                    psum += p;
                    Ps[(w * 2 + mb) * 1152 + (quad * 4 + r) * 72 + nb * 16 + l15] =
                        (_Float16)p;
                }
                lreg[mb][r] = lreg[mb][r] * alpha + psum;
                mreg[mb][r] = mnew;
#pragma unroll
                for (int nb = 0; nb < 4; ++nb) O[mb][nb][r] *= alpha;
            }
        }

        // P: C-layout -> A-layout via wave-private LDS
        __builtin_amdgcn_wave_barrier();
        WAIT_LGKM0();
        __builtin_amdgcn_wave_barrier();
        half8 pa0[2], pa1[2];
#pragma unroll
        for (int mb = 0; mb < 2; ++mb) {
            const _Float16* pp = Ps + (w * 2 + mb) * 1152 + l15 * 72 + quad * 8;
            pa0[mb] = *(const half8*)pp;
            pa1[mb] = *(const half8*)(pp + 32);
        }

        // PV: V B-frags, 8 coalesced 1KB loads, shared by both m-blocks
#pragma unroll
        for (int nb = 0; nb < 4; ++nb) {
            const _Float16* vp = VF + ((size_t)(t * 4 + nb) * 2) * 512 + lane * 8;
            const half8 v0 = *(const half8*)vp;
            const half8 v1 = *(const half8*)(vp + 512);
#pragma unroll
            for (int mb = 0; mb < 2; ++mb) {
                O[mb][nb] = MFMA16(pa0[mb], v0, O[mb][nb]);
                O[mb][nb] = MFMA16(pa1[mb], v1, O[mb][nb]);
            }
        }
        __builtin_amdgcn_wave_barrier();
    }

    // row-sum l across the 16-lane group
#pragma unroll
    for (int mb = 0; mb < 2; ++mb)
#pragma unroll
        for (int r = 0; r < 4; ++r) {
            float s = lreg[mb][r];
            s += __shfl_xor(s, 1);
            s += __shfl_xor(s, 2);
            s += __shfl_xor(s, 4);
            s += __shfl_xor(s, 8);
            lreg[mb][r] = s;
        }

    // ---- subsplit merge: waves ss=1 publish, waves ss=0 merge + write ----
    float* mO = smemf;                          // [mhalf][32][64] = 16 KB
    float* mM = smemf + 4096;                   // [mhalf][32]
    float* mL = smemf + 4160;                   // [mhalf][32]
    __syncthreads();
    if (ss == 1) {
#pragma unroll
        for (int mb = 0; mb < 2; ++mb)
#pragma unroll
            for (int r = 0; r < 4; ++r) {
                const int row32 = mb * 16 + quad * 4 + r;
#pragma unroll
                for (int nb = 0; nb < 4; ++nb)
                    mO[mhalf * 2048 + row32 * 64 + nb * 16 + l15] = O[mb][nb][r];
                if (l15 == 0) {
                    mM[mhalf * 32 + row32] = mreg[mb][r];
                    mL[mhalf * 32 + row32] = lreg[mb][r];
                }
            }
    }
    __syncthreads();
    if (ss == 0) {
        const int pidx = qt * NSPLIT + sp;
#pragma unroll
        for (int mb = 0; mb < 2; ++mb)
#pragma unroll
            for (int r = 0; r < 4; ++r) {
                const int row32 = mb * 16 + quad * 4 + r;
                const float m1 = mreg[mb][r], l1 = lreg[mb][r];
                const float m2 = mM[mhalf * 32 + row32];
                const float l2 = mL[mhalf * 32 + row32];
                const float mm = fmaxf(m1, m2);
                const float a1 = (m1 == -INFINITY) ? 0.f : EXP2F(m1 - mm);
                const float a2 = (m2 == -INFINITY) ? 0.f : EXP2F(m2 - mm);
                const int row = mhalf * 32 + row32;
                float* dst = po + ((size_t)pidx * 64 + row) * 64;
#pragma unroll
                for (int nb = 0; nb < 4; ++nb)
                    dst[nb * 16 + l15] =
                        O[mb][nb][r] * a1 + mO[mhalf * 2048 + row32 * 64 + nb * 16 + l15] * a2;
                if (l15 == 0) {
                    pm[pidx * 64 + row] = mm;
                    pl[pidx * 64 + row] = l1 * a1 + l2 * a2;
                }
            }
    }
}

// ---------------------------------------------------------------------------
// Kernel 3: merge the NSPLIT split-partials per row (exp2 domain).
// ---------------------------------------------------------------------------
__global__ __launch_bounds__(256) void combine_kernel(
    const float* __restrict__ pm, const float* __restrict__ pl,
    const float* __restrict__ po, float* __restrict__ out)
{
    const int idx = blockIdx.x * 256 + threadIdx.x;    // over T*H
    const int row = idx >> 6;
    const int d   = idx & 63;
    const int qt  = row >> 6;
    const int r   = row & 63;

    float mm = -INFINITY;
#pragma unroll
    for (int s = 0; s < NSPLIT; ++s)
        mm = fmaxf(mm, pm[(qt * NSPLIT + s) * 64 + r]);
    float L = 0.f, val = 0.f;
#pragma unroll
    for (int s = 0; s < NSPLIT; ++s) {
        const int p = (qt * NSPLIT + s) * 64 + r;
        const float mp = pm[p];
        const float sc = (mp > -INFINITY) ? EXP2F(mp - mm) : 0.f;
        L   += pl[p] * sc;
        val += po[(size_t)p * H_DIM + d] * sc;
    }
    out[idx] = val / L;
}

// ---------------------------------------------------------------------------
extern "C" void kernel_launch(void* const* d_in, const int* in_sizes, int n_in,
                              void* d_out, int out_size, void* d_ws, size_t ws_size,
                              hipStream_t stream)
{
    const float* tokens = (const float*)d_in[0];
    const float* Wk = (const float*)d_in[1];
    const float* Wq = (const float*)d_in[2];
    const float* Wv = (const float*)d_in[3];
    float* out = (float*)d_out;

    // ws layout (bytes), total 14.25 MB:
    //   WF @0 (576KB) | KF @1MB (2MB) | QF @3MB (2MB) | VF @5MB (1MB)
    //   pm @6MB (128KB) | pl @6.125MB (128KB) | po @6.25MB (8MB)
    char* ws = (char*)d_ws;
    const size_t MB = 1024 * 1024;
    _Float16* WF = (_Float16*)(ws + 0 * MB);
    _Float16* KF = (_Float16*)(ws + 1 * MB);
    _Float16* QF = (_Float16*)(ws + 3 * MB);
    _Float16* VF = (_Float16*)(ws + 5 * MB);
    float* pm = (float*)(ws + 6 * MB);
    float* pl = (float*)(ws + 6 * MB + 128 * 1024);
    float* po = (float*)(ws + 6 * MB + 256 * 1024);

    wconvert_kernel<<<288, 64, 0, stream>>>(Wk, Wq, Wv, WF);

    proj_kernel<<<768, 64, 0, stream>>>(tokens, WF, KF, QF, VF);

    attn_mfma_kernel<<<128 * NSPLIT, 256, 0, stream>>>(QF, KF, VF, pm, pl, po);

    combine_kernel<<<T_TOK * H_DIM / 256, 256, 0, stream>>>(pm, pl, po, out);
}

// Round 6
// 157.800 us; speedup vs baseline: 9.1979x; 1.0960x over previous
//
#include <hip/hip_runtime.h>
#include <math.h>

#define T_TOK 8192
#define C_DIM 768
#define H_DIM 64
// reference MULTIPLIES by c**0.5; we work in exp2 domain: scale * log2(e)
#define SCALE_LOG2E (27.712812921102035f * 1.4426950408889634f)
#define NSPLIT 4

typedef _Float16 half8 __attribute__((ext_vector_type(8)));
typedef float floatx4 __attribute__((ext_vector_type(4)));

#define MFMA16(a, b, c) __builtin_amdgcn_mfma_f32_16x16x32_f16(a, b, c, 0, 0, 0)
// wait lgkmcnt(0) only: vmcnt=0x3F, expcnt=7, lgkm=0
#define WAIT_LGKM0() __builtin_amdgcn_s_waitcnt(0xC07F)
#define EXP2F(x) __builtin_amdgcn_exp2f(x)

// Fragment layouts in workspace (all 1KB frags, perfectly coalesced b128/lane):
//   WF[mat][kt(24)][nb(4)][hl(2)][512 f16]   = W[kt*32+quad*8+j][nb*16+l15]
//   KF[t(128)][nb(4)][ks(2)][hl(2)][512 f16] = K[t*64+nb*16+l15][ks*32+quad*8+j]
//   QF[rb(512)][ks(2)][hl(2)][512 f16]       = Q[rb*16+l15][ks*32+quad*8+j]
//   VF[t(128)][nb(4)][ks(2)][512 f16]        = V[t*64+ks*32+quad*8+j][nb*16+l15]

// ---------------------------------------------------------------------------
// Kernel 0: W fp32 -> hi/lo f16 B-frags.  288 blocks x 64 threads.
// (byte-identical to the round-4 passing version)
// ---------------------------------------------------------------------------
__global__ __launch_bounds__(64) void wconvert_kernel(
    const float* __restrict__ Wk, const float* __restrict__ Wq,
    const float* __restrict__ Wv, _Float16* __restrict__ WF)
{
    const int b = blockIdx.x;                  // 3*24*4
    const int mat = b / 96, rem = b % 96, kt = rem >> 2, nb = rem & 3;
    const int lane = threadIdx.x & 63, l15 = lane & 15, quad = lane >> 4;
    const float* __restrict__ W = (mat == 0) ? Wk : (mat == 1) ? Wq : Wv;

    half8 h, l;
#pragma unroll
    for (int j = 0; j < 8; ++j) {
        const float v = W[(kt * 32 + quad * 8 + j) * H_DIM + nb * 16 + l15];
        const _Float16 hv = (_Float16)v;
        h[j] = hv;
        l[j] = (_Float16)(v - (float)hv);
    }
    _Float16* dst = WF + ((((size_t)mat * 24 + kt) * 4 + nb) * 2) * 512 + lane * 8;
    *(half8*)dst = h;
    *(half8*)(dst + 512) = l;
}

// ---------------------------------------------------------------------------
// Kernel 1: MFMA projection — round-4 body (768 blocks x 64 thr, 32 rows/wave,
// identical epilogue index math) + two surgical changes:
//   (a) 1-deep register prefetch of next-kt token/W loads (SSA rename only;
//       round 4 issued loads just-in-time -> ~200-900 cy exposed per iter,
//       VALUBusy 5%).
//   (b) Cb transpose stride 64 -> 68 floats (272B = 17x16B: b128-aligned,
//       bank step 4 -> free 2-way; stride 64 was 16-way, 180k conflict cy).
// ---------------------------------------------------------------------------
__global__ __launch_bounds__(64) void proj_kernel(
    const float* __restrict__ tokens, const _Float16* __restrict__ WF,
    _Float16* __restrict__ KF, _Float16* __restrict__ QF,
    _Float16* __restrict__ VF)
{
    __shared__ float Cb[32 * 68];              // 8.5 KB
    const int b = blockIdx.x;
    const int mat = b >> 8, mi = b & 255;
    const int lane = threadIdx.x & 63, l15 = lane & 15, quad = lane >> 4;
    const int row0 = mi * 32;

    floatx4 acc[2][4];
#pragma unroll
    for (int mb = 0; mb < 2; ++mb)
#pragma unroll
        for (int nb = 0; nb < 4; ++nb) acc[mb][nb] = 0;

    const _Float16* __restrict__ wfm = WF + (size_t)mat * 24 * 4 * 2 * 512;
    const float* __restrict__ xb0 = tokens + (size_t)(row0 + l15) * C_DIM + quad * 8;
    const float* __restrict__ xb1 = tokens + (size_t)(row0 + 16 + l15) * C_DIM + quad * 8;

    // prefetch kt = 0
    float4 nx[4];
    nx[0] = *(const float4*)(xb0);
    nx[1] = *(const float4*)(xb0 + 4);
    nx[2] = *(const float4*)(xb1);
    nx[3] = *(const float4*)(xb1 + 4);
    half8 nwh[4], nwl[4];
#pragma unroll
    for (int nb = 0; nb < 4; ++nb) {
        const _Float16* wp = wfm + ((size_t)nb * 2) * 512 + lane * 8;
        nwh[nb] = *(const half8*)wp;
        nwl[nb] = (mat != 2) ? *(const half8*)(wp + 512) : nwh[nb];
    }

    for (int kt = 0; kt < 24; ++kt) {
        // stage current iteration's operands
        const float4 x0 = nx[0], x1 = nx[1], x2 = nx[2], x3 = nx[3];
        half8 wh[4], wl[4];
#pragma unroll
        for (int nb = 0; nb < 4; ++nb) { wh[nb] = nwh[nb]; wl[nb] = nwl[nb]; }

        // issue next iteration's loads immediately (1-deep prefetch)
        const int ktn = (kt < 23) ? kt + 1 : 23;
        nx[0] = *(const float4*)(xb0 + ktn * 32);
        nx[1] = *(const float4*)(xb0 + ktn * 32 + 4);
        nx[2] = *(const float4*)(xb1 + ktn * 32);
        nx[3] = *(const float4*)(xb1 + ktn * 32 + 4);
#pragma unroll
        for (int nb = 0; nb < 4; ++nb) {
            const _Float16* wp = wfm + (((size_t)ktn * 4 + nb) * 2) * 512 + lane * 8;
            nwh[nb] = *(const half8*)wp;
            nwl[nb] = (mat != 2) ? *(const half8*)(wp + 512) : nwh[nb];
        }

        // convert current A-tiles to hi/lo f16 (as round 4)
        half8 ah[2], al[2];
        {
            const float xs0[8] = {x0.x, x0.y, x0.z, x0.w, x1.x, x1.y, x1.z, x1.w};
            const float xs1[8] = {x2.x, x2.y, x2.z, x2.w, x3.x, x3.y, x3.z, x3.w};
#pragma unroll
            for (int e = 0; e < 8; ++e) {
                _Float16 hv = (_Float16)xs0[e];
                ah[0][e] = hv;
                al[0][e] = (_Float16)(xs0[e] - (float)hv);
                hv = (_Float16)xs1[e];
                ah[1][e] = hv;
                al[1][e] = (_Float16)(xs1[e] - (float)hv);
            }
        }

#pragma unroll
        for (int nb = 0; nb < 4; ++nb) {
            if (mat != 2) {
#pragma unroll
                for (int mb = 0; mb < 2; ++mb) {
                    acc[mb][nb] = MFMA16(ah[mb], wh[nb], acc[mb][nb]);
                    acc[mb][nb] = MFMA16(ah[mb], wl[nb], acc[mb][nb]);
                    acc[mb][nb] = MFMA16(al[mb], wh[nb], acc[mb][nb]);
                }
            } else {
#pragma unroll
                for (int mb = 0; mb < 2; ++mb)
                    acc[mb][nb] = MFMA16(ah[mb], wh[nb], acc[mb][nb]);
            }
        }
    }

    // C-layout -> LDS (round-4 indexing, stride 68)
#pragma unroll
    for (int mb = 0; mb < 2; ++mb)
#pragma unroll
        for (int nb = 0; nb < 4; ++nb)
#pragma unroll
            for (int r = 0; r < 4; ++r)
                Cb[(mb * 16 + quad * 4 + r) * 68 + nb * 16 + l15] = acc[mb][nb][r];
    __builtin_amdgcn_wave_barrier();
    WAIT_LGKM0();
    __builtin_amdgcn_wave_barrier();

    if (mat != 2) {                            // K (mat 0) / Q (mat 1)
#pragma unroll
        for (int nbL = 0; nbL < 2; ++nbL) {
#pragma unroll
            for (int ks = 0; ks < 2; ++ks) {
                const float* cp = Cb + (nbL * 16 + l15) * 68 + ks * 32 + quad * 8;
                const float4 c0 = *(const float4*)cp;
                const float4 c1 = *(const float4*)(cp + 4);
                const float cs[8] = {c0.x, c0.y, c0.z, c0.w, c1.x, c1.y, c1.z, c1.w};
                half8 h, l;
#pragma unroll
                for (int e = 0; e < 8; ++e) {
                    const _Float16 hv = (_Float16)cs[e];
                    h[e] = hv;
                    l[e] = (_Float16)(cs[e] - (float)hv);
                }
                _Float16* dst;
                if (mat == 0) {
                    const int t = mi >> 1, nb = (mi & 1) * 2 + nbL;
                    dst = KF + (((size_t)(t * 4 + nb) * 2 + ks) * 2) * 512 + lane * 8;
                } else {
                    const int rb = mi * 2 + nbL;
                    dst = QF + (((size_t)rb * 2 + ks) * 2) * 512 + lane * 8;
                }
                *(half8*)dst = h;
                *(half8*)(dst + 512) = l;
            }
        }
    } else {                                   // V
        const int t = mi >> 1, ks = mi & 1;
#pragma unroll
        for (int nb = 0; nb < 4; ++nb) {
            half8 h;
#pragma unroll
            for (int j = 0; j < 8; ++j)
                h[j] = (_Float16)Cb[(quad * 8 + j) * 68 + nb * 16 + l15];
            *(half8*)(VF + ((size_t)(t * 4 + nb) * 2 + ks) * 512 + lane * 8) = h;
        }
    }
}

// ---------------------------------------------------------------------------
// Kernel 2: causal flash attention, all-coalesced frag loads.
// (byte-identical to the round-4 passing version)
// ---------------------------------------------------------------------------
__global__ __launch_bounds__(256, 2) void attn_mfma_kernel(
    const _Float16* __restrict__ QF, const _Float16* __restrict__ KF,
    const _Float16* __restrict__ VF,
    float* __restrict__ pm, float* __restrict__ pl, float* __restrict__ po)
{
    // Ps: [w][mb][16 rows][stride 72 f16] = 18432 B; merge phase reuses it.
    __shared__ __align__(16) float smemf[4608];
    _Float16* Ps = (_Float16*)smemf;

    const int w = threadIdx.x >> 6, lane = threadIdx.x & 63;
    const int l15 = lane & 15, quad = lane >> 4;
    const int mhalf = w & 1, ss = w >> 1;

    const int b = blockIdx.x;
    const int j = b & 255, hb = b >> 8;
    const int qt = (hb == 0) ? (j >> 1) : (127 - (j >> 1));
    const int sp = (hb << 1) | (j & 1);

    const int qbase = qt * 64;
    const int wrow0 = qbase + mhalf * 32;

    // Q A-frags (hi/lo), loaded once
    half8 qh[2][2], ql[2][2];
#pragma unroll
    for (int mb = 0; mb < 2; ++mb)
#pragma unroll
        for (int ks = 0; ks < 2; ++ks) {
            const int rb = qt * 4 + mhalf * 2 + mb;
            const _Float16* qp = QF + (((size_t)rb * 2 + ks) * 2) * 512 + lane * 8;
            qh[mb][ks] = *(const half8*)qp;
            ql[mb][ks] = *(const half8*)(qp + 512);
        }

    floatx4 O[2][4];
#pragma unroll
    for (int mb = 0; mb < 2; ++mb)
#pragma unroll
        for (int nb = 0; nb < 4; ++nb) O[mb][nb] = 0;
    float mreg[2][4], lreg[2][4];
#pragma unroll
    for (int mb = 0; mb < 2; ++mb)
#pragma unroll
        for (int r = 0; r < 4; ++r) { mreg[mb][r] = -INFINITY; lreg[mb][r] = 0.f; }

    for (int t = sp + 4 * ss; t <= qt; t += 8) {
        const int kb = t * 64;

        // K B-frags: 16 coalesced 1KB loads
        half8 bh[4][2], bl[4][2];
#pragma unroll
        for (int nb = 0; nb < 4; ++nb)
#pragma unroll
            for (int ks = 0; ks < 2; ++ks) {
                const _Float16* kp =
                    KF + (((size_t)(t * 4 + nb) * 2 + ks) * 2) * 512 + lane * 8;
                bh[nb][ks] = *(const half8*)kp;
                bl[nb][ks] = *(const half8*)(kp + 512);
            }

        // S = Q K^T (hi*hi + hi*lo + lo*hi), scaled into exp2 domain
        float sv[2][4][4];
#pragma unroll
        for (int mb = 0; mb < 2; ++mb)
#pragma unroll
            for (int nb = 0; nb < 4; ++nb) {
                floatx4 s = 0;
#pragma unroll
                for (int ks = 0; ks < 2; ++ks) {
                    s = MFMA16(qh[mb][ks], bh[nb][ks], s);
                    s = MFMA16(qh[mb][ks], bl[nb][ks], s);
                    s = MFMA16(ql[mb][ks], bh[nb][ks], s);
                }
#pragma unroll
                for (int r = 0; r < 4; ++r) sv[mb][nb][r] = s[r] * SCALE_LOG2E;
            }

        if (kb + 63 > wrow0) {                 // diagonal tile: causal mask
#pragma unroll
            for (int mb = 0; mb < 2; ++mb) {
                const int rowbase = wrow0 + mb * 16 + quad * 4;
#pragma unroll
                for (int nb = 0; nb < 4; ++nb) {
                    const int col = kb + nb * 16 + l15;
#pragma unroll
                    for (int r = 0; r < 4; ++r)
                        if (col > rowbase + r) sv[mb][nb][r] = -INFINITY;
                }
            }
        }

        // online softmax (exp2 domain)
#pragma unroll
        for (int mb = 0; mb < 2; ++mb) {
#pragma unroll
            for (int r = 0; r < 4; ++r) {
                float rm = fmaxf(fmaxf(sv[mb][0][r], sv[mb][1][r]),
                                 fmaxf(sv[mb][2][r], sv[mb][3][r]));
                rm = fmaxf(rm, __shfl_xor(rm, 1));
                rm = fmaxf(rm, __shfl_xor(rm, 2));
                rm = fmaxf(rm, __shfl_xor(rm, 4));
                rm = fmaxf(rm, __shfl_xor(rm, 8));
                const float mnew = fmaxf(mreg[mb][r], rm);
                const float alpha = EXP2F(mreg[mb][r] - mnew);   // -inf -> 0
                float psum = 0.f;
#pragma unroll
                for (int nb = 0; nb < 4; ++nb) {
                    const float p = EXP2F(sv[mb][nb][r] - mnew);  // -inf -> 0
                    psum += p;
                    Ps[(w * 2 + mb) * 1152 + (quad * 4 + r) * 72 + nb * 16 + l15] =
                        (_Float16)p;
                }
                lreg[mb][r] = lreg[mb][r] * alpha + psum;
                mreg[mb][r] = mnew;
#pragma unroll
                for (int nb = 0; nb < 4; ++nb) O[mb][nb][r] *= alpha;
            }
        }

        // P: C-layout -> A-layout via wave-private LDS
        __builtin_amdgcn_wave_barrier();
        WAIT_LGKM0();
        __builtin_amdgcn_wave_barrier();
        half8 pa0[2], pa1[2];
#pragma unroll
        for (int mb = 0; mb < 2; ++mb) {
            const _Float16* pp = Ps + (w * 2 + mb) * 1152 + l15 * 72 + quad * 8;
            pa0[mb] = *(const half8*)pp;
            pa1[mb] = *(const half8*)(pp + 32);
        }

        // PV: V B-frags, 8 coalesced 1KB loads, shared by both m-blocks
#pragma unroll
        for (int nb = 0; nb < 4; ++nb) {
            const _Float16* vp = VF + ((size_t)(t * 4 + nb) * 2) * 512 + lane * 8;
            const half8 v0 = *(const half8*)vp;
            const half8 v1 = *(const half8*)(vp + 512);
#pragma unroll
            for (int mb = 0; mb < 2; ++mb) {
                O[mb][nb] = MFMA16(pa0[mb], v0, O[mb][nb]);
                O[mb][nb] = MFMA16(pa1[mb], v1, O[mb][nb]);
            }
        }
        __builtin_amdgcn_wave_barrier();
    }

    // row-sum l across the 16-lane group
#pragma unroll
    for (int mb = 0; mb < 2; ++mb)
#pragma unroll
        for (int r = 0; r < 4; ++r) {
            float s = lreg[mb][r];
            s += __shfl_xor(s, 1);
            s += __shfl_xor(s, 2);
            s += __shfl_xor(s, 4);
            s += __shfl_xor(s, 8);
            lreg[mb][r] = s;
        }

    // ---- subsplit merge: waves ss=1 publish, waves ss=0 merge + write ----
    float* mO = smemf;                          // [mhalf][32][64] = 16 KB
    float* mM = smemf + 4096;                   // [mhalf][32]
    float* mL = smemf + 4160;                   // [mhalf][32]
    __syncthreads();
    if (ss == 1) {
#pragma unroll
        for (int mb = 0; mb < 2; ++mb)
#pragma unroll
            for (int r = 0; r < 4; ++r) {
                const int row32 = mb * 16 + quad * 4 + r;
#pragma unroll
                for (int nb = 0; nb < 4; ++nb)
                    mO[mhalf * 2048 + row32 * 64 + nb * 16 + l15] = O[mb][nb][r];
                if (l15 == 0) {
                    mM[mhalf * 32 + row32] = mreg[mb][r];
                    mL[mhalf * 32 + row32] = lreg[mb][r];
                }
            }
    }
    __syncthreads();
    if (ss == 0) {
        const int pidx = qt * NSPLIT + sp;
#pragma unroll
        for (int mb = 0; mb < 2; ++mb)
#pragma unroll
            for (int r = 0; r < 4; ++r) {
                const int row32 = mb * 16 + quad * 4 + r;
                const float m1 = mreg[mb][r], l1 = lreg[mb][r];
                const float m2 = mM[mhalf * 32 + row32];
                const float l2 = mL[mhalf * 32 + row32];
                const float mm = fmaxf(m1, m2);
                const float a1 = (m1 == -INFINITY) ? 0.f : EXP2F(m1 - mm);
                const float a2 = (m2 == -INFINITY) ? 0.f : EXP2F(m2 - mm);
                const int row = mhalf * 32 + row32;
                float* dst = po + ((size_t)pidx * 64 + row) * 64;
#pragma unroll
                for (int nb = 0; nb < 4; ++nb)
                    dst[nb * 16 + l15] =
                        O[mb][nb][r] * a1 + mO[mhalf * 2048 + row32 * 64 + nb * 16 + l15] * a2;
                if (l15 == 0) {
                    pm[pidx * 64 + row] = mm;
                    pl[pidx * 64 + row] = l1 * a1 + l2 * a2;
                }
            }
    }
}

// ---------------------------------------------------------------------------
// Kernel 3: merge the NSPLIT split-partials per row (exp2 domain).
// (byte-identical to the round-4 passing version)
// ---------------------------------------------------------------------------
__global__ __launch_bounds__(256) void combine_kernel(
    const float* __restrict__ pm, const float* __restrict__ pl,
    const float* __restrict__ po, float* __restrict__ out)
{
    const int idx = blockIdx.x * 256 + threadIdx.x;    // over T*H
    const int row = idx >> 6;
    const int d   = idx & 63;
    const int qt  = row >> 6;
    const int r   = row & 63;

    float mm = -INFINITY;
#pragma unroll
    for (int s = 0; s < NSPLIT; ++s)
        mm = fmaxf(mm, pm[(qt * NSPLIT + s) * 64 + r]);
    float L = 0.f, val = 0.f;
#pragma unroll
    for (int s = 0; s < NSPLIT; ++s) {
        const int p = (qt * NSPLIT + s) * 64 + r;
        const float mp = pm[p];
        const float sc = (mp > -INFINITY) ? EXP2F(mp - mm) : 0.f;
        L   += pl[p] * sc;
        val += po[(size_t)p * H_DIM + d] * sc;
    }
    out[idx] = val / L;
}

// ---------------------------------------------------------------------------
extern "C" void kernel_launch(void* const* d_in, const int* in_sizes, int n_in,
                              void* d_out, int out_size, void* d_ws, size_t ws_size,
                              hipStream_t stream)
{
    const float* tokens = (const float*)d_in[0];
    const float* Wk = (const float*)d_in[1];
    const float* Wq = (const float*)d_in[2];
    const float* Wv = (const float*)d_in[3];
    float* out = (float*)d_out;

    // ws layout (bytes), total 14.25 MB:
    //   WF @0 (576KB) | KF @1MB (2MB) | QF @3MB (2MB) | VF @5MB (1MB)
    //   pm @6MB (128KB) | pl @6.125MB (128KB) | po @6.25MB (8MB)
    char* ws = (char*)d_ws;
    const size_t MB = 1024 * 1024;
    _Float16* WF = (_Float16*)(ws + 0 * MB);
    _Float16* KF = (_Float16*)(ws + 1 * MB);
    _Float16* QF = (_Float16*)(ws + 3 * MB);
    _Float16* VF = (_Float16*)(ws + 5 * MB);
    float* pm = (float*)(ws + 6 * MB);
    float* pl = (float*)(ws + 6 * MB + 128 * 1024);
    float* po = (float*)(ws + 6 * MB + 256 * 1024);

    wconvert_kernel<<<288, 64, 0, stream>>>(Wk, Wq, Wv, WF);

    proj_kernel<<<768, 64, 0, stream>>>(tokens, WF, KF, QF, VF);

    attn_mfma_kernel<<<128 * NSPLIT, 256, 0, stream>>>(QF, KF, VF, pm, pl, po);

    combine_kernel<<<T_TOK * H_DIM / 256, 256, 0, stream>>>(pm, pl, po, out);
}

// Round 8
// 153.064 us; speedup vs baseline: 9.4825x; 1.0309x over previous
//
#include <hip/hip_runtime.h>
#include <math.h>

#define T_TOK 8192
#define C_DIM 768
#define H_DIM 64
// reference MULTIPLIES by c**0.5; we work in exp2 domain: scale * log2(e)
#define SCALE_LOG2E (27.712812921102035f * 1.4426950408889634f)
#define NSPLIT 4

typedef _Float16 half8 __attribute__((ext_vector_type(8)));
typedef float floatx4 __attribute__((ext_vector_type(4)));

#define MFMA16(a, b, c) __builtin_amdgcn_mfma_f32_16x16x32_f16(a, b, c, 0, 0, 0)
// wait lgkmcnt(0) only: vmcnt=0x3F, expcnt=7, lgkm=0
#define WAIT_LGKM0() __builtin_amdgcn_s_waitcnt(0xC07F)
#define EXP2F(x) __builtin_amdgcn_exp2f(x)

// Fragment layouts in workspace (all 1KB frags, perfectly coalesced b128/lane):
//   WF[mat][kt(24)][nb(4)][hl(2)][512 f16]   = W[kt*32+quad*8+j][nb*16+l15]
//   KF[t(128)][nb(4)][ks(2)][hl(2)][512 f16] = K[t*64+nb*16+l15][ks*32+quad*8+j]
//   QF[rb(512)][ks(2)][hl(2)][512 f16]       = Q[rb*16+l15][ks*32+quad*8+j]
//   VF[t(128)][nb(4)][ks(2)][512 f16]        = V[t*64+ks*32+quad*8+j][nb*16+l15]

// ---------------------------------------------------------------------------
// Kernel 0: W fp32 -> hi/lo f16 B-frags.  288 blocks x 64 threads.
// (byte-identical to the round-6 passing version)
// ---------------------------------------------------------------------------
__global__ __launch_bounds__(64) void wconvert_kernel(
    const float* __restrict__ Wk, const float* __restrict__ Wq,
    const float* __restrict__ Wv, _Float16* __restrict__ WF)
{
    const int b = blockIdx.x;                  // 3*24*4
    const int mat = b / 96, rem = b % 96, kt = rem >> 2, nb = rem & 3;
    const int lane = threadIdx.x & 63, l15 = lane & 15, quad = lane >> 4;
    const float* __restrict__ W = (mat == 0) ? Wk : (mat == 1) ? Wq : Wv;

    half8 h, l;
#pragma unroll
    for (int j = 0; j < 8; ++j) {
        const float v = W[(kt * 32 + quad * 8 + j) * H_DIM + nb * 16 + l15];
        const _Float16 hv = (_Float16)v;
        h[j] = hv;
        l[j] = (_Float16)(v - (float)hv);
    }
    _Float16* dst = WF + ((((size_t)mat * 24 + kt) * 4 + nb) * 2) * 512 + lane * 8;
    *(half8*)dst = h;
    *(half8*)(dst + 512) = l;
}

// ---------------------------------------------------------------------------
// Kernel 1: MFMA projection.
// (byte-identical to the round-6 PASSING version — the round-7 2-wave
// restructure is reverted wholesale as part of the bisect; proj restructures
// have now failed 2 of 2 attempts and this body is the proven one)
// ---------------------------------------------------------------------------
__global__ __launch_bounds__(64) void proj_kernel(
    const float* __restrict__ tokens, const _Float16* __restrict__ WF,
    _Float16* __restrict__ KF, _Float16* __restrict__ QF,
    _Float16* __restrict__ VF)
{
    __shared__ float Cb[32 * 68];              // 8.5 KB
    const int b = blockIdx.x;
    const int mat = b >> 8, mi = b & 255;
    const int lane = threadIdx.x & 63, l15 = lane & 15, quad = lane >> 4;
    const int row0 = mi * 32;

    floatx4 acc[2][4];
#pragma unroll
    for (int mb = 0; mb < 2; ++mb)
#pragma unroll
        for (int nb = 0; nb < 4; ++nb) acc[mb][nb] = 0;

    const _Float16* __restrict__ wfm = WF + (size_t)mat * 24 * 4 * 2 * 512;
    const float* __restrict__ xb0 = tokens + (size_t)(row0 + l15) * C_DIM + quad * 8;
    const float* __restrict__ xb1 = tokens + (size_t)(row0 + 16 + l15) * C_DIM + quad * 8;

    // prefetch kt = 0
    float4 nx[4];
    nx[0] = *(const float4*)(xb0);
    nx[1] = *(const float4*)(xb0 + 4);
    nx[2] = *(const float4*)(xb1);
    nx[3] = *(const float4*)(xb1 + 4);
    half8 nwh[4], nwl[4];
#pragma unroll
    for (int nb = 0; nb < 4; ++nb) {
        const _Float16* wp = wfm + ((size_t)nb * 2) * 512 + lane * 8;
        nwh[nb] = *(const half8*)wp;
        nwl[nb] = (mat != 2) ? *(const half8*)(wp + 512) : nwh[nb];
    }

    for (int kt = 0; kt < 24; ++kt) {
        // stage current iteration's operands
        const float4 x0 = nx[0], x1 = nx[1], x2 = nx[2], x3 = nx[3];
        half8 wh[4], wl[4];
#pragma unroll
        for (int nb = 0; nb < 4; ++nb) { wh[nb] = nwh[nb]; wl[nb] = nwl[nb]; }

        // issue next iteration's loads immediately (1-deep prefetch)
        const int ktn = (kt < 23) ? kt + 1 : 23;
        nx[0] = *(const float4*)(xb0 + ktn * 32);
        nx[1] = *(const float4*)(xb0 + ktn * 32 + 4);
        nx[2] = *(const float4*)(xb1 + ktn * 32);
        nx[3] = *(const float4*)(xb1 + ktn * 32 + 4);
#pragma unroll
        for (int nb = 0; nb < 4; ++nb) {
            const _Float16* wp = wfm + (((size_t)ktn * 4 + nb) * 2) * 512 + lane * 8;
            nwh[nb] = *(const half8*)wp;
            nwl[nb] = (mat != 2) ? *(const half8*)(wp + 512) : nwh[nb];
        }

        // convert current A-tiles to hi/lo f16 (as round 4)
        half8 ah[2], al[2];
        {
            const float xs0[8] = {x0.x, x0.y, x0.z, x0.w, x1.x, x1.y, x1.z, x1.w};
            const float xs1[8] = {x2.x, x2.y, x2.z, x2.w, x3.x, x3.y, x3.z, x3.w};
#pragma unroll
            for (int e = 0; e < 8; ++e) {
                _Float16 hv = (_Float16)xs0[e];
                ah[0][e] = hv;
                al[0][e] = (_Float16)(xs0[e] - (float)hv);
                hv = (_Float16)xs1[e];
                ah[1][e] = hv;
                al[1][e] = (_Float16)(xs1[e] - (float)hv);
            }
        }

#pragma unroll
        for (int nb = 0; nb < 4; ++nb) {
            if (mat != 2) {
#pragma unroll
                for (int mb = 0; mb < 2; ++mb) {
                    acc[mb][nb] = MFMA16(ah[mb], wh[nb], acc[mb][nb]);
                    acc[mb][nb] = MFMA16(ah[mb], wl[nb], acc[mb][nb]);
                    acc[mb][nb] = MFMA16(al[mb], wh[nb], acc[mb][nb]);
                }
            } else {
#pragma unroll
                for (int mb = 0; mb < 2; ++mb)
                    acc[mb][nb] = MFMA16(ah[mb], wh[nb], acc[mb][nb]);
            }
        }
    }

    // C-layout -> LDS (round-4 indexing, stride 68)
#pragma unroll
    for (int mb = 0; mb < 2; ++mb)
#pragma unroll
        for (int nb = 0; nb < 4; ++nb)
#pragma unroll
            for (int r = 0; r < 4; ++r)
                Cb[(mb * 16 + quad * 4 + r) * 68 + nb * 16 + l15] = acc[mb][nb][r];
    __builtin_amdgcn_wave_barrier();
    WAIT_LGKM0();
    __builtin_amdgcn_wave_barrier();

    if (mat != 2) {                            // K (mat 0) / Q (mat 1)
#pragma unroll
        for (int nbL = 0; nbL < 2; ++nbL) {
#pragma unroll
            for (int ks = 0; ks < 2; ++ks) {
                const float* cp = Cb + (nbL * 16 + l15) * 68 + ks * 32 + quad * 8;
                const float4 c0 = *(const float4*)cp;
                const float4 c1 = *(const float4*)(cp + 4);
                const float cs[8] = {c0.x, c0.y, c0.z, c0.w, c1.x, c1.y, c1.z, c1.w};
                half8 h, l;
#pragma unroll
                for (int e = 0; e < 8; ++e) {
                    const _Float16 hv = (_Float16)cs[e];
                    h[e] = hv;
                    l[e] = (_Float16)(cs[e] - (float)hv);
                }
                _Float16* dst;
                if (mat == 0) {
                    const int t = mi >> 1, nb = (mi & 1) * 2 + nbL;
                    dst = KF + (((size_t)(t * 4 + nb) * 2 + ks) * 2) * 512 + lane * 8;
                } else {
                    const int rb = mi * 2 + nbL;
                    dst = QF + (((size_t)rb * 2 + ks) * 2) * 512 + lane * 8;
                }
                *(half8*)dst = h;
                *(half8*)(dst + 512) = l;
            }
        }
    } else {                                   // V
        const int t = mi >> 1, ks = mi & 1;
#pragma unroll
        for (int nb = 0; nb < 4; ++nb) {
            half8 h;
#pragma unroll
            for (int j = 0; j < 8; ++j)
                h[j] = (_Float16)Cb[(quad * 8 + j) * 68 + nb * 16 + l15];
            *(half8*)(VF + ((size_t)(t * 4 + nb) * 2 + ks) * 512 + lane * 8) = h;
        }
    }
}

// ---------------------------------------------------------------------------
// Kernel 2: causal flash attention — round-6 proven body + in-wave software
// pipeline (the ONLY change this round, for the bisect):
//   (a) V-frags of tile t loaded at tile TOP (used ~600cy later, after
//       softmax);
//   (b) K-frags of tile t+8 issued right after the S-MFMAs consume the
//       current ones (land during softmax+PV).
// Pure load scheduling; Ps LDS round-trip, softmax, merge all byte-identical
// to round 6.
// ---------------------------------------------------------------------------
__global__ __launch_bounds__(256, 2) void attn_mfma_kernel(
    const _Float16* __restrict__ QF, const _Float16* __restrict__ KF,
    const _Float16* __restrict__ VF,
    float* __restrict__ pm, float* __restrict__ pl, float* __restrict__ po)
{
    // Ps: [w][mb][16 rows][stride 72 f16] = 18432 B; merge phase reuses it.
    __shared__ __align__(16) float smemf[4608];
    _Float16* Ps = (_Float16*)smemf;

    const int w = threadIdx.x >> 6, lane = threadIdx.x & 63;
    const int l15 = lane & 15, quad = lane >> 4;
    const int mhalf = w & 1, ss = w >> 1;

    const int b = blockIdx.x;
    const int j = b & 255, hb = b >> 8;
    const int qt = (hb == 0) ? (j >> 1) : (127 - (j >> 1));
    const int sp = (hb << 1) | (j & 1);

    const int qbase = qt * 64;
    const int wrow0 = qbase + mhalf * 32;

    // Q A-frags (hi/lo), loaded once
    half8 qh[2][2], ql[2][2];
#pragma unroll
    for (int mb = 0; mb < 2; ++mb)
#pragma unroll
        for (int ks = 0; ks < 2; ++ks) {
            const int rb = qt * 4 + mhalf * 2 + mb;
            const _Float16* qp = QF + (((size_t)rb * 2 + ks) * 2) * 512 + lane * 8;
            qh[mb][ks] = *(const half8*)qp;
            ql[mb][ks] = *(const half8*)(qp + 512);
        }

    floatx4 O[2][4];
#pragma unroll
    for (int mb = 0; mb < 2; ++mb)
#pragma unroll
        for (int nb = 0; nb < 4; ++nb) O[mb][nb] = 0;
    float mreg[2][4], lreg[2][4];
#pragma unroll
    for (int mb = 0; mb < 2; ++mb)
#pragma unroll
        for (int r = 0; r < 4; ++r) { mreg[mb][r] = -INFINITY; lreg[mb][r] = 0.f; }

    const int t0 = sp + 4 * ss;
    half8 bh[4][2], bl[4][2];
    if (t0 <= qt) {                            // preload first tile's K frags
#pragma unroll
        for (int nb = 0; nb < 4; ++nb)
#pragma unroll
            for (int ks = 0; ks < 2; ++ks) {
                const _Float16* kp =
                    KF + (((size_t)(t0 * 4 + nb) * 2 + ks) * 2) * 512 + lane * 8;
                bh[nb][ks] = *(const half8*)kp;
                bl[nb][ks] = *(const half8*)(kp + 512);
            }
    }

    for (int t = t0; t <= qt; t += 8) {
        const int kb = t * 64;

        // V frags of THIS tile: issued ~600cy before their PV use
        half8 v0r[4], v1r[4];
#pragma unroll
        for (int nb = 0; nb < 4; ++nb) {
            const _Float16* vp = VF + ((size_t)(t * 4 + nb) * 2) * 512 + lane * 8;
            v0r[nb] = *(const half8*)vp;
            v1r[nb] = *(const half8*)(vp + 512);
        }

        // S = Q K^T (hi*hi + hi*lo + lo*hi), scaled into exp2 domain
        float sv[2][4][4];
#pragma unroll
        for (int mb = 0; mb < 2; ++mb)
#pragma unroll
            for (int nb = 0; nb < 4; ++nb) {
                floatx4 s = 0;
#pragma unroll
                for (int ks = 0; ks < 2; ++ks) {
                    s = MFMA16(qh[mb][ks], bh[nb][ks], s);
                    s = MFMA16(qh[mb][ks], bl[nb][ks], s);
                    s = MFMA16(ql[mb][ks], bh[nb][ks], s);
                }
#pragma unroll
                for (int r = 0; r < 4; ++r) sv[mb][nb][r] = s[r] * SCALE_LOG2E;
            }

        // prefetch NEXT tile's K frags (current ones are dead after S)
        if (t + 8 <= qt) {
            const int tn = t + 8;
#pragma unroll
            for (int nb = 0; nb < 4; ++nb)
#pragma unroll
                for (int ks = 0; ks < 2; ++ks) {
                    const _Float16* kp =
                        KF + (((size_t)(tn * 4 + nb) * 2 + ks) * 2) * 512 + lane * 8;
                    bh[nb][ks] = *(const half8*)kp;
                    bl[nb][ks] = *(const half8*)(kp + 512);
                }
        }

        if (kb + 63 > wrow0) {                 // diagonal tile: causal mask
#pragma unroll
            for (int mb = 0; mb < 2; ++mb) {
                const int rowbase = wrow0 + mb * 16 + quad * 4;
#pragma unroll
                for (int nb = 0; nb < 4; ++nb) {
                    const int col = kb + nb * 16 + l15;
#pragma unroll
                    for (int r = 0; r < 4; ++r)
                        if (col > rowbase + r) sv[mb][nb][r] = -INFINITY;
                }
            }
        }

        // online softmax (exp2 domain)
#pragma unroll
        for (int mb = 0; mb < 2; ++mb) {
#pragma unroll
            for (int r = 0; r < 4; ++r) {
                float rm = fmaxf(fmaxf(sv[mb][0][r], sv[mb][1][r]),
                                 fmaxf(sv[mb][2][r], sv[mb][3][r]));
                rm = fmaxf(rm, __shfl_xor(rm, 1));
                rm = fmaxf(rm, __shfl_xor(rm, 2));
                rm = fmaxf(rm, __shfl_xor(rm, 4));
                rm = fmaxf(rm, __shfl_xor(rm, 8));
                const float mnew = fmaxf(mreg[mb][r], rm);
                const float alpha = EXP2F(mreg[mb][r] - mnew);   // -inf -> 0
                float psum = 0.f;
#pragma unroll
                for (int nb = 0; nb < 4; ++nb) {
                    const float p = EXP2F(sv[mb][nb][r] - mnew);  // -inf -> 0
                    psum += p;
                    Ps[(w * 2 + mb) * 1152 + (quad * 4 + r) * 72 + nb * 16 + l15] =
                        (_Float16)p;
                }
                lreg[mb][r] = lreg[mb][r] * alpha + psum;
                mreg[mb][r] = mnew;
#pragma unroll
                for (int nb = 0; nb < 4; ++nb) O[mb][nb][r] *= alpha;
            }
        }

        // P: C-layout -> A-layout via wave-private LDS
        __builtin_amdgcn_wave_barrier();
        WAIT_LGKM0();
        __builtin_amdgcn_wave_barrier();
        half8 pa0[2], pa1[2];
#pragma unroll
        for (int mb = 0; mb < 2; ++mb) {
            const _Float16* pp = Ps + (w * 2 + mb) * 1152 + l15 * 72 + quad * 8;
            pa0[mb] = *(const half8*)pp;
            pa1[mb] = *(const half8*)(pp + 32);
        }

        // PV with the V frags loaded at tile top
#pragma unroll
        for (int nb = 0; nb < 4; ++nb) {
#pragma unroll
            for (int mb = 0; mb < 2; ++mb) {
                O[mb][nb] = MFMA16(pa0[mb], v0r[nb], O[mb][nb]);
                O[mb][nb] = MFMA16(pa1[mb], v1r[nb], O[mb][nb]);
            }
        }
        __builtin_amdgcn_wave_barrier();
    }

    // row-sum l across the 16-lane group
#pragma unroll
    for (int mb = 0; mb < 2; ++mb)
#pragma unroll
        for (int r = 0; r < 4; ++r) {
            float s = lreg[mb][r];
            s += __shfl_xor(s, 1);
            s += __shfl_xor(s, 2);
            s += __shfl_xor(s, 4);
            s += __shfl_xor(s, 8);
            lreg[mb][r] = s;
        }

    // ---- subsplit merge: waves ss=1 publish, waves ss=0 merge + write ----
    float* mO = smemf;                          // [mhalf][32][64] = 16 KB
    float* mM = smemf + 4096;                   // [mhalf][32]
    float* mL = smemf + 4160;                   // [mhalf][32]
    __syncthreads();
    if (ss == 1) {
#pragma unroll
        for (int mb = 0; mb < 2; ++mb)
#pragma unroll
            for (int r = 0; r < 4; ++r) {
                const int row32 = mb * 16 + quad * 4 + r;
#pragma unroll
                for (int nb = 0; nb < 4; ++nb)
                    mO[mhalf * 2048 + row32 * 64 + nb * 16 + l15] = O[mb][nb][r];
                if (l15 == 0) {
                    mM[mhalf * 32 + row32] = mreg[mb][r];
                    mL[mhalf * 32 + row32] = lreg[mb][r];
                }
            }
    }
    __syncthreads();
    if (ss == 0) {
        const int pidx = qt * NSPLIT + sp;
#pragma unroll
        for (int mb = 0; mb < 2; ++mb)
#pragma unroll
            for (int r = 0; r < 4; ++r) {
                const int row32 = mb * 16 + quad * 4 + r;
                const float m1 = mreg[mb][r], l1 = lreg[mb][r];
                const float m2 = mM[mhalf * 32 + row32];
                const float l2 = mL[mhalf * 32 + row32];
                const float mm = fmaxf(m1, m2);
                const float a1 = (m1 == -INFINITY) ? 0.f : EXP2F(m1 - mm);
                const float a2 = (m2 == -INFINITY) ? 0.f : EXP2F(m2 - mm);
                const int row = mhalf * 32 + row32;
                float* dst = po + ((size_t)pidx * 64 + row) * 64;
#pragma unroll
                for (int nb = 0; nb < 4; ++nb)
                    dst[nb * 16 + l15] =
                        O[mb][nb][r] * a1 + mO[mhalf * 2048 + row32 * 64 + nb * 16 + l15] * a2;
                if (l15 == 0) {
                    pm[pidx * 64 + row] = mm;
                    pl[pidx * 64 + row] = l1 * a1 + l2 * a2;
                }
            }
    }
}

// ---------------------------------------------------------------------------
// Kernel 3: merge the NSPLIT split-partials per row (exp2 domain).
// (byte-identical to the round-6 passing version)
// ---------------------------------------------------------------------------
__global__ __launch_bounds__(256) void combine_kernel(
    const float* __restrict__ pm, const float* __restrict__ pl,
    const float* __restrict__ po, float* __restrict__ out)
{
    const int idx = blockIdx.x * 256 + threadIdx.x;    // over T*H
    const int row = idx >> 6;
    const int d   = idx & 63;
    const int qt  = row >> 6;
    const int r   = row & 63;

    float mm = -INFINITY;
#pragma unroll
    for (int s = 0; s < NSPLIT; ++s)
        mm = fmaxf(mm, pm[(qt * NSPLIT + s) * 64 + r]);
    float L = 0.f, val = 0.f;
#pragma unroll
    for (int s = 0; s < NSPLIT; ++s) {
        const int p = (qt * NSPLIT + s) * 64 + r;
        const float mp = pm[p];
        const float sc = (mp > -INFINITY) ? EXP2F(mp - mm) : 0.f;
        L   += pl[p] * sc;
        val += po[(size_t)p * H_DIM + d] * sc;
    }
    out[idx] = val / L;
}

// ---------------------------------------------------------------------------
extern "C" void kernel_launch(void* const* d_in, const int* in_sizes, int n_in,
                              void* d_out, int out_size, void* d_ws, size_t ws_size,
                              hipStream_t stream)
{
    const float* tokens = (const float*)d_in[0];
    const float* Wk = (const float*)d_in[1];
    const float* Wq = (const float*)d_in[2];
    const float* Wv = (const float*)d_in[3];
    float* out = (float*)d_out;

    // ws layout (bytes), total 14.25 MB:
    //   WF @0 (576KB) | KF @1MB (2MB) | QF @3MB (2MB) | VF @5MB (1MB)
    //   pm @6MB (128KB) | pl @6.125MB (128KB) | po @6.25MB (8MB)
    char* ws = (char*)d_ws;
    const size_t MB = 1024 * 1024;
    _Float16* WF = (_Float16*)(ws + 0 * MB);
    _Float16* KF = (_Float16*)(ws + 1 * MB);
    _Float16* QF = (_Float16*)(ws + 3 * MB);
    _Float16* VF = (_Float16*)(ws + 5 * MB);
    float* pm = (float*)(ws + 6 * MB);
    float* pl = (float*)(ws + 6 * MB + 128 * 1024);
    float* po = (float*)(ws + 6 * MB + 256 * 1024);

    wconvert_kernel<<<288, 64, 0, stream>>>(Wk, Wq, Wv, WF);

    proj_kernel<<<768, 64, 0, stream>>>(tokens, WF, KF, QF, VF);

    attn_mfma_kernel<<<128 * NSPLIT, 256, 0, stream>>>(QF, KF, VF, pm, pl, po);

    combine_kernel<<<T_TOK * H_DIM / 256, 256, 0, stream>>>(pm, pl, po, out);
}